// Round 1
// baseline (486.804 us; speedup 1.0000x reference)
//
#include <hip/hip_runtime.h>
#include <hip/hip_bf16.h>
#include <stdint.h>

#define B_ 4
#define N_ 4096
#define D_ 256
#define K_ 64
#define BN_ (B_*N_)
#define QS 264   // LDS row stride (bf16 elems) for q/k tiles
#define SS 68    // LDS row stride (floats) for S tile

typedef __attribute__((ext_vector_type(8))) short bf16x8;
typedef __attribute__((ext_vector_type(4))) float f32x4;

static __device__ __forceinline__ unsigned short f2bf(float f) {
  union { float f; unsigned u; } x; x.f = f;
  unsigned r = x.u + 0x7fffu + ((x.u >> 16) & 1u);
  return (unsigned short)(r >> 16);
}
static __device__ __forceinline__ float bf2f(unsigned short u) {
  union { unsigned u; float f; } x; x.u = ((unsigned)u) << 16;
  return x.f;
}
static __device__ __forceinline__ f32x4 mfma16(bf16x8 a, bf16x8 b, f32x4 c) {
  return __builtin_amdgcn_mfma_f32_16x16x32_bf16(a, b, c, 0, 0, 0);
}

// ---------------- kernel 1: L2-normalize rows, save norms ----------------
__global__ __launch_bounds__(256) void normalize_kernel(
    const float* __restrict__ x, unsigned short* __restrict__ xn,
    float* __restrict__ norms) {
  int row = blockIdx.x * 4 + (threadIdx.x >> 6);
  int lane = threadIdx.x & 63;
  const float4 v = reinterpret_cast<const float4*>(x + (size_t)row * D_)[lane];
  float ss = v.x*v.x + v.y*v.y + v.z*v.z + v.w*v.w;
  #pragma unroll
  for (int off = 32; off > 0; off >>= 1) ss += __shfl_xor(ss, off);
  float nrm = sqrtf(ss);
  float scale = 1.0f / fmaxf(nrm, 1e-12f);
  ushort4 o;
  o.x = f2bf(v.x * scale); o.y = f2bf(v.y * scale);
  o.z = f2bf(v.z * scale); o.w = f2bf(v.w * scale);
  reinterpret_cast<ushort4*>(xn + (size_t)row * D_)[lane] = o;
  if (lane == 0) norms[row] = nrm;
}

// ---------------- kernel 2: W fp32 -> bf16 ----------------
__global__ __launch_bounds__(256) void wconv_kernel(
    const float* __restrict__ W, unsigned short* __restrict__ Wb) {
  int i = blockIdx.x * 256 + threadIdx.x;
  float4 v = reinterpret_cast<const float4*>(W)[i];
  ushort4 o; o.x = f2bf(v.x); o.y = f2bf(v.y); o.z = f2bf(v.z); o.w = f2bf(v.w);
  reinterpret_cast<ushort4*>(Wb)[i] = o;
}

// ---------------- kernel 3: value = (xn*norm) @ W^T + b  (bf16), vsum fp32 ----
__global__ __launch_bounds__(256, 2) void value_kernel(
    const unsigned short* __restrict__ xn, const float* __restrict__ norms,
    const unsigned short* __restrict__ Wb, const float* __restrict__ bias,
    unsigned short* __restrict__ value, float* __restrict__ vsum) {
  __shared__ __attribute__((aligned(16))) unsigned short xs[64 * QS];
  __shared__ float ns[64];
  const int t = threadIdx.x, lane = t & 63, w = t >> 6;
  const int row0 = blockIdx.x * 64;
  #pragma unroll
  for (int i = 0; i < 8; i++) {
    int cid = t + i * 256;
    int r = cid >> 5, c = cid & 31;
    *reinterpret_cast<float4*>(&xs[r*QS + c*8]) =
      *reinterpret_cast<const float4*>(&xn[(size_t)(row0 + r)*D_ + c*8]);
  }
  if (t < 64) ns[t] = norms[row0 + t];
  __syncthreads();
  const int l15 = lane & 15, lk = (lane >> 4) * 8;
  f32x4 acc[4][4];
  #pragma unroll
  for (int i = 0; i < 4; i++)
    #pragma unroll
    for (int j = 0; j < 4; j++) acc[i][j] = (f32x4){0.f,0.f,0.f,0.f};
  #pragma unroll
  for (int ks = 0; ks < 8; ks++) {
    bf16x8 a[4], bb[4];
    #pragma unroll
    for (int at = 0; at < 4; at++)
      a[at] = *reinterpret_cast<const bf16x8*>(&xs[(at*16 + l15)*QS + ks*32 + lk]);
    #pragma unroll
    for (int bt = 0; bt < 4; bt++)
      bb[bt] = *reinterpret_cast<const bf16x8*>(&Wb[(size_t)(w*64 + bt*16 + l15)*D_ + ks*32 + lk]);
    #pragma unroll
    for (int at = 0; at < 4; at++)
      #pragma unroll
      for (int bt = 0; bt < 4; bt++)
        acc[at][bt] = mfma16(a[at], bb[bt], acc[at][bt]);
  }
  float vpart[4] = {0.f, 0.f, 0.f, 0.f};
  const int rb = (lane >> 4) * 4;
  #pragma unroll
  for (int at = 0; at < 4; at++) {
    #pragma unroll
    for (int bt = 0; bt < 4; bt++) {
      int e = w*64 + bt*16 + l15;
      float be = bias[e];
      #pragma unroll
      for (int reg = 0; reg < 4; reg++) {
        int r = at*16 + rb + reg;
        float v = acc[at][bt][reg] * ns[r] + be;
        value[(size_t)(row0 + r)*D_ + e] = f2bf(v);
        vpart[bt] += v;
      }
    }
  }
  int b = row0 >> 12;
  #pragma unroll
  for (int bt = 0; bt < 4; bt++)
    atomicAdd(&vsum[b*D_ + w*64 + bt*16 + l15], vpart[bt]);
}

// ---------------- kernel 4: fused cos-sim + streaming top-64 + sparse softmax @ V ----
__global__ __launch_bounds__(256, 2) void main_kernel(
    const unsigned short* __restrict__ xn,
    const unsigned short* __restrict__ value,
    const float* __restrict__ vsum,
    float* __restrict__ out) {
  __shared__ __attribute__((aligned(16))) unsigned char smem[63488];
  unsigned short* q_lds  = (unsigned short*)smem;            // [32][QS] (staging only)
  unsigned short* k_lds  = (unsigned short*)(smem + 16896);  // [64][QS]
  float*          Sf     = (float*)(smem + 50688);           // [32][SS]
  unsigned short* tk_idx = (unsigned short*)(smem + 59392);  // [32][64]
  // overlay of q region once a-frags are in registers:
  float*          tk_val = (float*)smem;                     // [32][64]
  unsigned short* queue  = (unsigned short*)(smem + 8192);   // [32][64]
  int*            qcnt   = (int*)(smem + 12288);             // [32]
  float*          gmin   = (float*)(smem + 12416);           // [32][8]
  int*            gpos   = (int*)(smem + 13440);             // [32][8]
  float*          minv   = (float*)(smem + 14464);           // [32]
  int*            minpos = (int*)(smem + 14592);             // [32]
  float*          Zrow   = (float*)(smem + 14720);           // [32]

  const int t = threadIdx.x, lane = t & 63, w = t >> 6;
  const int b = blockIdx.x >> 7;
  const int row0 = (blockIdx.x & 127) * 32;
  const size_t base_n = (size_t)b * N_;

  // stage q rows
  #pragma unroll
  for (int i = 0; i < 4; i++) {
    int cid = t + i * 256; int r = cid >> 5, c = cid & 31;
    *reinterpret_cast<float4*>(&q_lds[r*QS + c*8]) =
      *reinterpret_cast<const float4*>(&xn[(base_n + row0 + r)*D_ + c*8]);
  }
  __syncthreads();
  const int l15 = lane & 15, lk = (lane >> 4) * 8;
  bf16x8 afrag[2][8];
  #pragma unroll
  for (int qs = 0; qs < 2; qs++)
    #pragma unroll
    for (int ks = 0; ks < 8; ks++)
      afrag[qs][ks] = *reinterpret_cast<const bf16x8*>(&q_lds[(qs*16 + l15)*QS + ks*32 + lk]);
  __syncthreads();  // q region free -> topk overlay

  for (int ct = 0; ct < 64; ct++) {
    // stage 64 key rows
    #pragma unroll
    for (int i = 0; i < 8; i++) {
      int cid = t + i * 256; int r = cid >> 5, c = cid & 31;
      *reinterpret_cast<float4*>(&k_lds[r*QS + c*8]) =
        *reinterpret_cast<const float4*>(&xn[(base_n + (size_t)ct*64 + r)*D_ + c*8]);
    }
    __syncthreads();
    // S tile [32 q][64 k]: wave w covers keys w*16..w*16+15, both q halves
    f32x4 acc0 = {0.f,0.f,0.f,0.f}, acc1 = {0.f,0.f,0.f,0.f};
    #pragma unroll
    for (int ks = 0; ks < 8; ks++) {
      bf16x8 bfr = *reinterpret_cast<const bf16x8*>(&k_lds[(w*16 + l15)*QS + ks*32 + lk]);
      acc0 = mfma16(afrag[0][ks], bfr, acc0);
      acc1 = mfma16(afrag[1][ks], bfr, acc1);
    }
    const int col = w*16 + l15, rb = (lane >> 4) * 4;
    #pragma unroll
    for (int reg = 0; reg < 4; reg++) {
      Sf[(rb + reg)*SS + col]      = acc0[reg];
      Sf[(16 + rb + reg)*SS + col] = acc1[reg];
    }
    __syncthreads();
    if (ct == 0) {
      // fill list with the first 64 columns
      { int r = t >> 3, c0 = (t & 7) * 8;
        #pragma unroll
        for (int j = 0; j < 8; j++) {
          tk_val[r*64 + c0 + j] = Sf[r*SS + c0 + j];
          tk_idx[r*64 + c0 + j] = (unsigned short)(c0 + j);
        } }
      __syncthreads();
      if (t < 32) {
        int r = t; float mv = 3.0e38f; int mp = 0;
        for (int g = 0; g < 8; g++) {
          float gm = tk_val[r*64 + g*8]; int gp = g*8;
          for (int j = 1; j < 8; j++) {
            float u = tk_val[r*64 + g*8 + j];
            if (u < gm) { gm = u; gp = g*8 + j; }
          }
          gmin[r*8 + g] = gm; gpos[r*8 + g] = gp;
          if (gm < mv) { mv = gm; mp = gp; }
        }
        minv[r] = mv; minpos[r] = mp; qcnt[r] = 0;
      }
    } else {
      // phase A: parallel threshold filter -> per-row queue
      { int r = t >> 3, c0 = (t & 7) * 8;
        float thr = minv[r];
        #pragma unroll
        for (int j = 0; j < 8; j++) {
          float v = Sf[r*SS + c0 + j];
          if (v > thr) {
            int p = atomicAdd(&qcnt[r], 1);
            queue[r*64 + p] = (unsigned short)(c0 + j);
          }
        } }
      __syncthreads();
      // phase B: serial exact insert per row
      if (t < 32) {
        int r = t, cnt = qcnt[r];
        for (int q = 0; q < cnt; q++) {
          int c = queue[r*64 + q];
          float v = Sf[r*SS + c];
          if (v > minv[r]) {
            int mp = minpos[r];
            tk_val[r*64 + mp] = v;
            tk_idx[r*64 + mp] = (unsigned short)(ct*64 + c);
            int g = mp >> 3;
            float gm = tk_val[r*64 + g*8]; int gp = g*8;
            for (int j = 1; j < 8; j++) {
              float u = tk_val[r*64 + g*8 + j];
              if (u < gm) { gm = u; gp = g*8 + j; }
            }
            gmin[r*8 + g] = gm; gpos[r*8 + g] = gp;
            float mv = gmin[r*8]; int mg = 0;
            for (int gg = 1; gg < 8; gg++) {
              float u = gmin[r*8 + gg];
              if (u < mv) { mv = u; mg = gg; }
            }
            minv[r] = mv; minpos[r] = gpos[r*8 + mg];
          }
        }
        qcnt[r] = 0;
      }
    }
    __syncthreads();
  }

  // epilogue: exp, Z, gather
  { int r = t >> 3, c0 = (t & 7) * 8;
    #pragma unroll
    for (int j = 0; j < 8; j++)
      Sf[r*SS + c0 + j] = __expf(tk_val[r*64 + c0 + j]); }
  __syncthreads();
  if (t < 32) {
    float s = 0.f;
    for (int i = 0; i < 64; i++) s += Sf[t*SS + i];
    Zrow[t] = s + (float)(N_ - K_);
  }
  __syncthreads();
  float4 vs = *reinterpret_cast<const float4*>(&vsum[b*D_ + lane*4]);
  for (int rr = 0; rr < 8; rr++) {
    int r = w*8 + rr;
    float ax = vs.x, ay = vs.y, az = vs.z, aw = vs.w;
    for (int i = 0; i < 64; i++) {
      float wgt = Sf[r*SS + i] - 1.0f;
      int idx = tk_idx[r*64 + i];
      ushort4 vv = *reinterpret_cast<const ushort4*>(&value[(base_n + (size_t)idx)*D_ + lane*4]);
      ax += wgt * bf2f(vv.x);
      ay += wgt * bf2f(vv.y);
      az += wgt * bf2f(vv.z);
      aw += wgt * bf2f(vv.w);
    }
    float iz = 1.0f / Zrow[r];
    float4 o; o.x = ax*iz; o.y = ay*iz; o.z = az*iz; o.w = aw*iz;
    *reinterpret_cast<float4*>(&out[(base_n + row0 + r)*D_ + lane*4]) = o;
  }
}

extern "C" void kernel_launch(void* const* d_in, const int* in_sizes, int n_in,
                              void* d_out, int out_size, void* d_ws, size_t ws_size,
                              hipStream_t stream) {
  const float* x    = (const float*)d_in[0];
  const float* W    = (const float*)d_in[1];
  const float* bias = (const float*)d_in[2];
  float* out = (float*)d_out;
  char* ws = (char*)d_ws;
  unsigned short* xn    = (unsigned short*)(ws);              //  8 MB  bf16 normed x
  unsigned short* Wb    = (unsigned short*)(ws + 8388608);    // 128 KB bf16 W
  float*          norms = (float*)(ws + 8519680);             //  64 KB
  unsigned short* value = (unsigned short*)(ws + 8585216);    //  8 MB  bf16 value
  float*          vsum  = (float*)(ws + 16973824);            //   4 KB

  hipMemsetAsync(vsum, 0, B_ * D_ * sizeof(float), stream);
  normalize_kernel<<<BN_/4, 256, 0, stream>>>(x, xn, norms);
  wconv_kernel<<<64, 256, 0, stream>>>(W, Wb);
  value_kernel<<<BN_/64, 256, 0, stream>>>(xn, norms, Wb, bias, value, vsum);
  main_kernel<<<BN_/32, 256, 0, stream>>>(xn, value, vsum, out);
}

// Round 3
// 357.013 us; speedup vs baseline: 1.3635x; 1.3635x over previous
//
#include <hip/hip_runtime.h>
#include <hip/hip_bf16.h>
#include <stdint.h>

#define B_ 4
#define N_ 4096
#define D_ 256
#define K_ 64
#define BN_ (B_*N_)
#define QS 264   // LDS row stride (bf16 elems) for staged tiles

typedef __attribute__((ext_vector_type(8))) short bf16x8;
typedef __attribute__((ext_vector_type(8))) unsigned short u16x8;
typedef __attribute__((ext_vector_type(4))) float f32x4;

static __device__ __forceinline__ unsigned short f2bf(float f) {
  union { float f; unsigned u; } x; x.f = f;
  unsigned r = x.u + 0x7fffu + ((x.u >> 16) & 1u);
  return (unsigned short)(r >> 16);
}
static __device__ __forceinline__ float bf2f(unsigned short u) {
  union { unsigned u; float f; } x; x.u = ((unsigned)u) << 16;
  return x.f;
}
static __device__ __forceinline__ f32x4 mfma16(bf16x8 a, bf16x8 b, f32x4 c) {
  return __builtin_amdgcn_mfma_f32_16x16x32_bf16(a, b, c, 0, 0, 0);
}

// ---------------- kernel 1: L2-normalize rows, save norms ----------------
__global__ __launch_bounds__(256) void normalize_kernel(
    const float* __restrict__ x, unsigned short* __restrict__ xn,
    float* __restrict__ norms) {
  int row = blockIdx.x * 4 + (threadIdx.x >> 6);
  int lane = threadIdx.x & 63;
  const float4 v = reinterpret_cast<const float4*>(x + (size_t)row * D_)[lane];
  float ss = v.x*v.x + v.y*v.y + v.z*v.z + v.w*v.w;
  #pragma unroll
  for (int off = 32; off > 0; off >>= 1) ss += __shfl_xor(ss, off);
  float nrm = sqrtf(ss);
  float scale = 1.0f / fmaxf(nrm, 1e-12f);
  ushort4 o;
  o.x = f2bf(v.x * scale); o.y = f2bf(v.y * scale);
  o.z = f2bf(v.z * scale); o.w = f2bf(v.w * scale);
  reinterpret_cast<ushort4*>(xn + (size_t)row * D_)[lane] = o;
  if (lane == 0) norms[row] = nrm;
}

// ---------------- kernel 2: W fp32 -> bf16 ----------------
__global__ __launch_bounds__(256) void wconv_kernel(
    const float* __restrict__ W, unsigned short* __restrict__ Wb) {
  int i = blockIdx.x * 256 + threadIdx.x;
  float4 v = reinterpret_cast<const float4*>(W)[i];
  ushort4 o; o.x = f2bf(v.x); o.y = f2bf(v.y); o.z = f2bf(v.z); o.w = f2bf(v.w);
  reinterpret_cast<ushort4*>(Wb)[i] = o;
}

// ---------------- kernel 3: value = (xn*norm) @ W^T + b  (bf16), vsum fp32 ----
__global__ __launch_bounds__(256, 2) void value_kernel(
    const unsigned short* __restrict__ xn, const float* __restrict__ norms,
    const unsigned short* __restrict__ Wb, const float* __restrict__ bias,
    unsigned short* __restrict__ value, float* __restrict__ vsum) {
  __shared__ __attribute__((aligned(16))) unsigned short xs[64 * QS];
  __shared__ float ns[64];
  const int t = threadIdx.x, lane = t & 63, w = t >> 6;
  const int row0 = blockIdx.x * 64;
  #pragma unroll
  for (int i = 0; i < 8; i++) {
    int cid = t + i * 256;
    int r = cid >> 5, c = cid & 31;
    *reinterpret_cast<float4*>(&xs[r*QS + c*8]) =
      *reinterpret_cast<const float4*>(&xn[(size_t)(row0 + r)*D_ + c*8]);
  }
  if (t < 64) ns[t] = norms[row0 + t];
  __syncthreads();
  const int l15 = lane & 15, lk = (lane >> 4) * 8;
  f32x4 acc[4][4];
  #pragma unroll
  for (int i = 0; i < 4; i++)
    #pragma unroll
    for (int j = 0; j < 4; j++) acc[i][j] = (f32x4){0.f,0.f,0.f,0.f};
  #pragma unroll
  for (int ks = 0; ks < 8; ks++) {
    bf16x8 a[4], bb[4];
    #pragma unroll
    for (int at = 0; at < 4; at++)
      a[at] = *reinterpret_cast<const bf16x8*>(&xs[(at*16 + l15)*QS + ks*32 + lk]);
    #pragma unroll
    for (int bt = 0; bt < 4; bt++)
      bb[bt] = *reinterpret_cast<const bf16x8*>(&Wb[(size_t)(w*64 + bt*16 + l15)*D_ + ks*32 + lk]);
    #pragma unroll
    for (int at = 0; at < 4; at++)
      #pragma unroll
      for (int bt = 0; bt < 4; bt++)
        acc[at][bt] = mfma16(a[at], bb[bt], acc[at][bt]);
  }
  float vpart[4] = {0.f, 0.f, 0.f, 0.f};
  const int rb = (lane >> 4) * 4;
  #pragma unroll
  for (int at = 0; at < 4; at++) {
    #pragma unroll
    for (int bt = 0; bt < 4; bt++) {
      int e = w*64 + bt*16 + l15;
      float be = bias[e];
      #pragma unroll
      for (int reg = 0; reg < 4; reg++) {
        int r = at*16 + rb + reg;
        float v = acc[at][bt][reg] * ns[r] + be;
        value[(size_t)(row0 + r)*D_ + e] = f2bf(v);
        vpart[bt] += v;
      }
    }
  }
  int b = row0 >> 12;
  #pragma unroll
  for (int bt = 0; bt < 4; bt++)
    atomicAdd(&vsum[b*D_ + w*64 + bt*16 + l15], vpart[bt]);
}

// ---------------- kernel 4: S = Xn @ Xn^T (one batch), bf16 out ----------------
// block: 256 rows x 64 cols. B (cols) staged in LDS once; A frags from global (L2).
__global__ __launch_bounds__(256, 2) void gemm_s_kernel(
    const unsigned short* __restrict__ xnb, unsigned short* __restrict__ S) {
  __shared__ __attribute__((aligned(16))) unsigned short Bs[64 * QS];
  __shared__ __attribute__((aligned(16))) unsigned short wsb[4][16][72];
  const int t = threadIdx.x, lane = t & 63, w = t >> 6;
  const int r0 = (blockIdx.x & 15) * 256;
  const int c0 = (blockIdx.x >> 4) * 64;
  #pragma unroll
  for (int i = 0; i < 8; i++) {
    int cid = t + i * 256; int r = cid >> 5, c = cid & 31;
    *reinterpret_cast<float4*>(&Bs[r*QS + c*8]) =
      *reinterpret_cast<const float4*>(&xnb[(size_t)(c0 + r)*D_ + c*8]);
  }
  __syncthreads();
  const int l15 = lane & 15, lk = (lane >> 4) * 8, rb = (lane >> 4) * 4;
  bf16x8 bfr[4][8];
  #pragma unroll
  for (int ct = 0; ct < 4; ct++)
    #pragma unroll
    for (int ks = 0; ks < 8; ks++)
      bfr[ct][ks] = *reinterpret_cast<const bf16x8*>(&Bs[(ct*16 + l15)*QS + ks*32 + lk]);
  f32x4 acc[4][4];
  #pragma unroll
  for (int i = 0; i < 4; i++)
    #pragma unroll
    for (int j = 0; j < 4; j++) acc[i][j] = (f32x4){0.f,0.f,0.f,0.f};
  const int rowbase = r0 + w * 64;
  #pragma unroll
  for (int rt = 0; rt < 4; rt++) {
    bf16x8 af[8];
    #pragma unroll
    for (int ks = 0; ks < 8; ks++)
      af[ks] = *reinterpret_cast<const bf16x8*>(
          &xnb[(size_t)(rowbase + rt*16 + l15)*D_ + ks*32 + lk]);
    #pragma unroll
    for (int ks = 0; ks < 8; ks++)
      #pragma unroll
      for (int ct = 0; ct < 4; ct++)
        acc[rt][ct] = mfma16(af[ks], bfr[ct][ks], acc[rt][ct]);
  }
  // epilogue: LDS transpose bounce per row-tile, coalesced bf16 stores
  #pragma unroll
  for (int rt = 0; rt < 4; rt++) {
    #pragma unroll
    for (int ct = 0; ct < 4; ct++)
      #pragma unroll
      for (int reg = 0; reg < 4; reg++)
        wsb[w][rb + reg][ct*16 + l15] = f2bf(acc[rt][ct][reg]);
    #pragma unroll
    for (int g = 0; g < 4; g++) {
      int row = g*4 + (lane >> 4);
      ushort4 d = *reinterpret_cast<const ushort4*>(&wsb[w][row][l15*4]);
      *reinterpret_cast<ushort4*>(
          &S[(size_t)(rowbase + rt*16 + row)*N_ + c0 + l15*4]) = d;
    }
  }
}

// ---------------- kernel 5: per-row radix-select top-64 + sparse softmax @ V ----
// one block (256 thr) per row. S row bf16 -> ordered u16 in regs; 2x8-bit
// histogram select (exact, ties by ticket -- tied scores have equal weights).
__global__ __launch_bounds__(256, 4) void select_kernel(
    const unsigned short* __restrict__ S,
    const unsigned short* __restrict__ value,
    const float* __restrict__ vsum,
    float* __restrict__ out, int b) {
  __shared__ unsigned int bins[256];
  __shared__ unsigned int sfx[256];
  __shared__ int widx_s[64];
  __shared__ float wv_s[64];
  __shared__ float partial[4][256];
  __shared__ int hb_s, cgthi_s, lb_s, cgtlo_s, nsel_s, neq_s;
  __shared__ float Z_s;

  const int t = threadIdx.x;
  const int r = blockIdx.x;
  const unsigned short* srow = S + (size_t)r * N_;

  u16x8 va = *reinterpret_cast<const u16x8*>(srow + t*16);
  u16x8 vb = *reinterpret_cast<const u16x8*>(srow + t*16 + 8);
  unsigned ov[16];
  #pragma unroll
  for (int j = 0; j < 8; j++) {
    unsigned short ba = va[j], bb = vb[j];
    ov[j]     = (ba & 0x8000u) ? (unsigned)((~ba) & 0xFFFFu) : (unsigned)(ba | 0x8000u);
    ov[j + 8] = (bb & 0x8000u) ? (unsigned)((~bb) & 0xFFFFu) : (unsigned)(bb | 0x8000u);
  }
  bins[t] = 0;
  if (t == 0) { nsel_s = 0; neq_s = 0; Z_s = 0.f; }
  __syncthreads();
  #pragma unroll
  for (int j = 0; j < 16; j++) atomicAdd(&bins[ov[j] >> 8], 1u);
  __syncthreads();
  sfx[t] = bins[t];
  __syncthreads();
  #pragma unroll
  for (int off = 1; off < 256; off <<= 1) {
    unsigned xx = sfx[t] + ((t + off < 256) ? sfx[t + off] : 0u);
    __syncthreads();
    sfx[t] = xx;
    __syncthreads();
  }
  {
    unsigned here = sfx[t], nxt = (t < 255) ? sfx[t + 1] : 0u;
    if (here >= 64u && nxt < 64u) { hb_s = t; cgthi_s = (int)nxt; }
  }
  __syncthreads();
  const int hb = hb_s;
  const int need2 = 64 - cgthi_s;
  bins[t] = 0;
  __syncthreads();
  #pragma unroll
  for (int j = 0; j < 16; j++)
    if ((int)(ov[j] >> 8) == hb) atomicAdd(&bins[ov[j] & 255u], 1u);
  __syncthreads();
  sfx[t] = bins[t];
  __syncthreads();
  #pragma unroll
  for (int off = 1; off < 256; off <<= 1) {
    unsigned xx = sfx[t] + ((t + off < 256) ? sfx[t + off] : 0u);
    __syncthreads();
    sfx[t] = xx;
    __syncthreads();
  }
  {
    unsigned here = sfx[t], nxt = (t < 255) ? sfx[t + 1] : 0u;
    if (here >= (unsigned)need2 && nxt < (unsigned)need2) { lb_s = t; cgtlo_s = (int)nxt; }
  }
  __syncthreads();
  const unsigned tau = ((unsigned)hb << 8) | (unsigned)lb_s;
  const int needeq = need2 - cgtlo_s;
  #pragma unroll
  for (int j = 0; j < 16; j++) {
    unsigned u = ov[j];
    bool take = false;
    if (u > tau) take = true;
    else if (u == tau) { int k = atomicAdd(&neq_s, 1); take = (k < needeq); }
    if (take) {
      int slot = atomicAdd(&nsel_s, 1);
      unsigned short bits = (u & 0x8000u) ? (unsigned short)(u & 0x7FFFu)
                                          : (unsigned short)((~u) & 0xFFFFu);
      float s = bf2f(bits);
      float e = __expf(s);
      atomicAdd(&Z_s, e);
      widx_s[slot] = t*16 + j;
      wv_s[slot] = e - 1.0f;
    }
  }
  __syncthreads();
  const float Z = Z_s + (float)(N_ - K_);
  const int lane = t & 63, w = t >> 6;
  const size_t vbase = (size_t)b * N_ * D_;
  float ax = 0.f, ay = 0.f, az = 0.f, aw = 0.f;
  #pragma unroll
  for (int i = 0; i < 16; i++) {
    int sel = w*16 + i;
    int idx = widx_s[sel];
    float wt = wv_s[sel];
    ushort4 vv = *reinterpret_cast<const ushort4*>(&value[vbase + (size_t)idx*D_ + lane*4]);
    ax += wt * bf2f(vv.x);
    ay += wt * bf2f(vv.y);
    az += wt * bf2f(vv.z);
    aw += wt * bf2f(vv.w);
  }
  partial[w][lane*4 + 0] = ax;
  partial[w][lane*4 + 1] = ay;
  partial[w][lane*4 + 2] = az;
  partial[w][lane*4 + 3] = aw;
  __syncthreads();
  float ps = partial[0][t] + partial[1][t] + partial[2][t] + partial[3][t];
  out[((size_t)b * N_ + r) * D_ + t] = (ps + vsum[b*D_ + t]) * (1.0f / Z);
}

extern "C" void kernel_launch(void* const* d_in, const int* in_sizes, int n_in,
                              void* d_out, int out_size, void* d_ws, size_t ws_size,
                              hipStream_t stream) {
  const float* x    = (const float*)d_in[0];
  const float* W    = (const float*)d_in[1];
  const float* bias = (const float*)d_in[2];
  float* out = (float*)d_out;
  char* ws = (char*)d_ws;
  unsigned short* xn    = (unsigned short*)(ws);              //  8 MB  bf16 normed x
  unsigned short* Wb    = (unsigned short*)(ws + 8388608);    // 128 KB bf16 W
  float*          norms = (float*)(ws + 8519680);             //  64 KB
  unsigned short* value = (unsigned short*)(ws + 8585216);    //  8 MB  bf16 value
  float*          vsum  = (float*)(ws + 16973824);            //   4 KB
  unsigned short* S     = (unsigned short*)(ws + 16977920);   // 32 MB  bf16 S (one batch)

  hipMemsetAsync(vsum, 0, B_ * D_ * sizeof(float), stream);
  normalize_kernel<<<BN_/4, 256, 0, stream>>>(x, xn, norms);
  wconv_kernel<<<64, 256, 0, stream>>>(W, Wb);
  value_kernel<<<BN_/64, 256, 0, stream>>>(xn, norms, Wb, bias, value, vsum);
  for (int b = 0; b < B_; b++) {
    gemm_s_kernel<<<1024, 256, 0, stream>>>(xn + (size_t)b * N_ * D_, S);
    select_kernel<<<N_, 256, 0, stream>>>(S, value, vsum, out, b);
  }
}

// Round 5
// 294.996 us; speedup vs baseline: 1.6502x; 1.2102x over previous
//
#include <hip/hip_runtime.h>
#include <hip/hip_bf16.h>
#include <stdint.h>

#define B_ 4
#define N_ 4096
#define D_ 256
#define K_ 64
#define BN_ (B_*N_)
#define QS 264   // LDS row stride (bf16 elems) for staged tiles

typedef __attribute__((ext_vector_type(8))) short bf16x8;
typedef __attribute__((ext_vector_type(8))) unsigned short u16x8;
typedef __attribute__((ext_vector_type(4))) float f32x4;

static __device__ __forceinline__ unsigned short f2bf(float f) {
  union { float f; unsigned u; } x; x.f = f;
  unsigned r = x.u + 0x7fffu + ((x.u >> 16) & 1u);
  return (unsigned short)(r >> 16);
}
static __device__ __forceinline__ float bf2f(unsigned short u) {
  union { unsigned u; float f; } x; x.u = ((unsigned)u) << 16;
  return x.f;
}
static __device__ __forceinline__ f32x4 mfma16(bf16x8 a, bf16x8 b, f32x4 c) {
  return __builtin_amdgcn_mfma_f32_16x16x32_bf16(a, b, c, 0, 0, 0);
}

// ---------------- kernel 1: normalize rows + W->bf16 + vsum zero ----------------
__global__ __launch_bounds__(256) void prep_kernel(
    const float* __restrict__ x, const float* __restrict__ W,
    unsigned short* __restrict__ xn, float* __restrict__ norms,
    unsigned short* __restrict__ Wb, float* __restrict__ vsum) {
  const int bid = blockIdx.x;
  if (bid < 4096) {
    int row = bid * 4 + (threadIdx.x >> 6);
    int lane = threadIdx.x & 63;
    const float4 v = reinterpret_cast<const float4*>(x + (size_t)row * D_)[lane];
    float ss = v.x*v.x + v.y*v.y + v.z*v.z + v.w*v.w;
    #pragma unroll
    for (int off = 32; off > 0; off >>= 1) ss += __shfl_xor(ss, off);
    float nrm = sqrtf(ss);
    float scale = 1.0f / fmaxf(nrm, 1e-12f);
    ushort4 o;
    o.x = f2bf(v.x * scale); o.y = f2bf(v.y * scale);
    o.z = f2bf(v.z * scale); o.w = f2bf(v.w * scale);
    reinterpret_cast<ushort4*>(xn + (size_t)row * D_)[lane] = o;
    if (lane == 0) norms[row] = nrm;
  } else if (bid < 4160) {
    int i = (bid - 4096) * 256 + threadIdx.x;
    float4 v = reinterpret_cast<const float4*>(W)[i];
    ushort4 o; o.x = f2bf(v.x); o.y = f2bf(v.y); o.z = f2bf(v.z); o.w = f2bf(v.w);
    reinterpret_cast<ushort4*>(Wb)[i] = o;
  } else {
    reinterpret_cast<float4*>(vsum)[threadIdx.x] = (float4){0.f, 0.f, 0.f, 0.f};
  }
}

// ---------------- kernel 2: value GEMM (blocks 0..255) + S GEMMs (blocks 256..4351) ----
// S stored as ORDERED u16 keys (monotone map of bf16) for the select kernel.
__global__ __launch_bounds__(256, 2) void compute_kernel(
    const unsigned short* __restrict__ xn, const float* __restrict__ norms,
    const unsigned short* __restrict__ Wb, const float* __restrict__ bias,
    unsigned short* __restrict__ value, float* __restrict__ vsum,
    unsigned short* __restrict__ S) {
  __shared__ __attribute__((aligned(16))) unsigned char smem[43520];
  unsigned short* tile = (unsigned short*)smem;             // [64*QS] both paths
  float*          ns   = (float*)(smem + 33792);            // value path [64]
  unsigned short* wsb  = (unsigned short*)(smem + 34048);   // gemm path [4][16][72]

  const int t = threadIdx.x, lane = t & 63, w = t >> 6;
  const int l15 = lane & 15, lk = (lane >> 4) * 8, rb = (lane >> 4) * 4;

  if (blockIdx.x < 256) {
    // ---- value = (xn*norm) @ W^T + b (bf16), vsum += column sums ----
    const int row0 = blockIdx.x * 64;
    #pragma unroll
    for (int i = 0; i < 8; i++) {
      int cid = t + i * 256;
      int r = cid >> 5, c = cid & 31;
      *reinterpret_cast<float4*>(&tile[r*QS + c*8]) =
        *reinterpret_cast<const float4*>(&xn[(size_t)(row0 + r)*D_ + c*8]);
    }
    if (t < 64) ns[t] = norms[row0 + t];
    __syncthreads();
    f32x4 acc[4][4];
    #pragma unroll
    for (int i = 0; i < 4; i++)
      #pragma unroll
      for (int j = 0; j < 4; j++) acc[i][j] = (f32x4){0.f,0.f,0.f,0.f};
    #pragma unroll
    for (int ks = 0; ks < 8; ks++) {
      bf16x8 a[4], bb[4];
      #pragma unroll
      for (int at = 0; at < 4; at++)
        a[at] = *reinterpret_cast<const bf16x8*>(&tile[(at*16 + l15)*QS + ks*32 + lk]);
      #pragma unroll
      for (int bt = 0; bt < 4; bt++)
        bb[bt] = *reinterpret_cast<const bf16x8*>(&Wb[(size_t)(w*64 + bt*16 + l15)*D_ + ks*32 + lk]);
      #pragma unroll
      for (int at = 0; at < 4; at++)
        #pragma unroll
        for (int bt = 0; bt < 4; bt++)
          acc[at][bt] = mfma16(a[at], bb[bt], acc[at][bt]);
    }
    float vpart[4] = {0.f, 0.f, 0.f, 0.f};
    #pragma unroll
    for (int at = 0; at < 4; at++) {
      #pragma unroll
      for (int bt = 0; bt < 4; bt++) {
        int e = w*64 + bt*16 + l15;
        float be = bias[e];
        #pragma unroll
        for (int reg = 0; reg < 4; reg++) {
          int r = at*16 + rb + reg;
          float v = acc[at][bt][reg] * ns[r] + be;
          value[(size_t)(row0 + r)*D_ + e] = f2bf(v);
          vpart[bt] += v;
        }
      }
    }
    int b = row0 >> 12;
    #pragma unroll
    for (int bt = 0; bt < 4; bt++)
      atomicAdd(&vsum[b*D_ + w*64 + bt*16 + l15], vpart[bt]);
  } else {
    // ---- S tile: 256 rows x 64 cols of Xn @ Xn^T for one batch ----
    const int g = blockIdx.x - 256;
    const int b = g >> 10;
    const int tl = g & 1023;
    const int r0 = (tl & 15) * 256;
    const int c0 = (tl >> 4) * 64;
    const unsigned short* xnb = xn + ((size_t)b << 20);
    unsigned short* Sb = S + ((size_t)b << 24);
    #pragma unroll
    for (int i = 0; i < 8; i++) {
      int cid = t + i * 256; int r = cid >> 5, c = cid & 31;
      *reinterpret_cast<float4*>(&tile[r*QS + c*8]) =
        *reinterpret_cast<const float4*>(&xnb[(size_t)(c0 + r)*D_ + c*8]);
    }
    __syncthreads();
    bf16x8 bfr[4][8];
    #pragma unroll
    for (int ct = 0; ct < 4; ct++)
      #pragma unroll
      for (int ks = 0; ks < 8; ks++)
        bfr[ct][ks] = *reinterpret_cast<const bf16x8*>(&tile[(ct*16 + l15)*QS + ks*32 + lk]);
    f32x4 acc[4][4];
    #pragma unroll
    for (int i = 0; i < 4; i++)
      #pragma unroll
      for (int j = 0; j < 4; j++) acc[i][j] = (f32x4){0.f,0.f,0.f,0.f};
    const int rowbase = r0 + w * 64;
    #pragma unroll
    for (int rt = 0; rt < 4; rt++) {
      bf16x8 af[8];
      #pragma unroll
      for (int ks = 0; ks < 8; ks++)
        af[ks] = *reinterpret_cast<const bf16x8*>(
            &xnb[(size_t)(rowbase + rt*16 + l15)*D_ + ks*32 + lk]);
      #pragma unroll
      for (int ks = 0; ks < 8; ks++)
        #pragma unroll
        for (int ct = 0; ct < 4; ct++)
          acc[rt][ct] = mfma16(af[ks], bfr[ct][ks], acc[rt][ct]);
    }
    // epilogue: bf16 -> ordered u16 key, LDS transpose bounce, coalesced stores
    unsigned short* myw = wsb + w * 16 * 72;
    #pragma unroll
    for (int rt = 0; rt < 4; rt++) {
      #pragma unroll
      for (int ct = 0; ct < 4; ct++)
        #pragma unroll
        for (int reg = 0; reg < 4; reg++) {
          unsigned short bits = f2bf(acc[rt][ct][reg]);
          unsigned short key = (bits & 0x8000u) ? (unsigned short)(~bits)
                                                : (unsigned short)(bits | 0x8000u);
          myw[(rb + reg)*72 + ct*16 + l15] = key;
        }
      #pragma unroll
      for (int g2 = 0; g2 < 4; g2++) {
        int row = g2*4 + (lane >> 4);
        ushort4 d = *reinterpret_cast<const ushort4*>(&myw[row*72 + l15*4]);
        *reinterpret_cast<ushort4*>(
            &Sb[(size_t)(rowbase + rt*16 + row)*N_ + c0 + l15*4]) = d;
      }
    }
  }
}

// ---------------- kernel 3: per-row radix-select top-64 + sparse softmax @ V ----
// one block per row, all batches in one grid. Wave-privatized histograms,
// shfl suffix scans, no float atomics.
__global__ __launch_bounds__(256, 4) void select_kernel(
    const unsigned short* __restrict__ S,
    const unsigned short* __restrict__ value,
    const float* __restrict__ vsum,
    float* __restrict__ out) {
  __shared__ unsigned bins[4][256];
  __shared__ unsigned wt4[4];
  __shared__ float zred[4];
  __shared__ int hb_s, cg_s, lb_s, cglo_s, nsel_s, neq_s;
  __shared__ int widx_s[64];
  __shared__ float wv_s[64];
  __shared__ float partial[4][256];

  const int t = threadIdx.x, lane = t & 63, w = t >> 6;
  const int b = blockIdx.x >> 12;
  const int r = blockIdx.x & 4095;
  const unsigned short* srow = S + ((size_t)b << 24) + ((size_t)r << 12);

  u16x8 va = *reinterpret_cast<const u16x8*>(srow + t*16);
  u16x8 vb = *reinterpret_cast<const u16x8*>(srow + t*16 + 8);
  unsigned ov[16];
  #pragma unroll
  for (int j = 0; j < 8; j++) { ov[j] = (unsigned short)va[j]; ov[j+8] = (unsigned short)vb[j]; }

  bins[0][t] = 0; bins[1][t] = 0; bins[2][t] = 0; bins[3][t] = 0;
  if (t == 0) { nsel_s = 0; neq_s = 0; }
  __syncthreads();                                          // B0
  #pragma unroll
  for (int j = 0; j < 16; j++) atomicAdd(&bins[w][ov[j] >> 8], 1u);
  __syncthreads();                                          // B1
  // suffix scan over 256 byte-bins (bin index = t)
  unsigned own = bins[0][t] + bins[1][t] + bins[2][t] + bins[3][t];
  unsigned v = own;
  #pragma unroll
  for (int off = 1; off < 64; off <<= 1) {
    unsigned o = __shfl_down(v, off);
    if (lane + off < 64) v += o;
  }
  if (lane == 0) wt4[w] = v;
  __syncthreads();                                          // B2
  unsigned sfx = v;
  #pragma unroll
  for (int ww = 0; ww < 4; ww++) if (ww > w) sfx += wt4[ww];
  unsigned nxt = sfx - own;
  if (sfx >= 64u && nxt < 64u) { hb_s = t; cg_s = (int)nxt; }
  __syncthreads();                                          // B3
  const unsigned hb = (unsigned)hb_s;
  const unsigned need2 = (unsigned)(64 - cg_s);             // >= 1 guaranteed
  bins[0][t] = 0; bins[1][t] = 0; bins[2][t] = 0; bins[3][t] = 0;
  __syncthreads();                                          // B4
  #pragma unroll
  for (int j = 0; j < 16; j++)
    if ((ov[j] >> 8) == hb) atomicAdd(&bins[w][ov[j] & 255u], 1u);
  __syncthreads();                                          // B5
  unsigned own2 = bins[0][t] + bins[1][t] + bins[2][t] + bins[3][t];
  unsigned v2 = own2;
  #pragma unroll
  for (int off = 1; off < 64; off <<= 1) {
    unsigned o = __shfl_down(v2, off);
    if (lane + off < 64) v2 += o;
  }
  if (lane == 0) wt4[w] = v2;
  __syncthreads();                                          // B6
  unsigned sfx2 = v2;
  #pragma unroll
  for (int ww = 0; ww < 4; ww++) if (ww > w) sfx2 += wt4[ww];
  unsigned nxt2 = sfx2 - own2;
  if (sfx2 >= need2 && nxt2 < need2) { lb_s = t; cglo_s = (int)nxt2; }
  __syncthreads();                                          // B7
  const unsigned tau = (hb << 8) | (unsigned)lb_s;
  const int needeq = (int)need2 - cglo_s;                   // >= 1 guaranteed

  float zloc = 0.f;
  #pragma unroll
  for (int j = 0; j < 16; j++) {
    unsigned u = ov[j];
    bool take = (u > tau);
    if (!take && u == tau) { int k = atomicAdd(&neq_s, 1); take = (k < needeq); }
    if (take) {
      int slot = atomicAdd(&nsel_s, 1);
      unsigned short bits = (u & 0x8000u) ? (unsigned short)(u & 0x7FFFu)
                                          : (unsigned short)(~u);
      float s = bf2f(bits);
      float e = __expf(s);
      zloc += e;
      widx_s[slot] = t*16 + j;
      wv_s[slot] = e - 1.0f;
    }
  }
  #pragma unroll
  for (int off = 32; off > 0; off >>= 1) zloc += __shfl_xor(zloc, off);
  if (lane == 0) zred[w] = zloc;
  __syncthreads();                                          // B8
  const float Z = zred[0] + zred[1] + zred[2] + zred[3] + (float)(N_ - K_);

  const size_t vbase = (size_t)b << 20;   // b*N*D
  float ax = 0.f, ay = 0.f, az = 0.f, aw = 0.f;
  #pragma unroll
  for (int i = 0; i < 16; i++) {
    int sel = w*16 + i;
    int idx = widx_s[sel];
    float wt = wv_s[sel];
    ushort4 vv = *reinterpret_cast<const ushort4*>(&value[vbase + (size_t)idx*D_ + lane*4]);
    ax += wt * bf2f(vv.x);
    ay += wt * bf2f(vv.y);
    az += wt * bf2f(vv.z);
    aw += wt * bf2f(vv.w);
  }
  partial[w][lane*4 + 0] = ax;
  partial[w][lane*4 + 1] = ay;
  partial[w][lane*4 + 2] = az;
  partial[w][lane*4 + 3] = aw;
  __syncthreads();                                          // B9
  float ps = partial[0][t] + partial[1][t] + partial[2][t] + partial[3][t];
  out[(((size_t)b << 12) + r) * D_ + t] = (ps + vsum[b*D_ + t]) * (1.0f / Z);
}

extern "C" void kernel_launch(void* const* d_in, const int* in_sizes, int n_in,
                              void* d_out, int out_size, void* d_ws, size_t ws_size,
                              hipStream_t stream) {
  const float* x    = (const float*)d_in[0];
  const float* W    = (const float*)d_in[1];
  const float* bias = (const float*)d_in[2];
  float* out = (float*)d_out;
  char* ws = (char*)d_ws;
  unsigned short* xn    = (unsigned short*)(ws);              //  8 MB  bf16 normed x
  unsigned short* Wb    = (unsigned short*)(ws + 8388608);    // 128 KB bf16 W
  float*          norms = (float*)(ws + 8519680);             //  64 KB
  unsigned short* value = (unsigned short*)(ws + 8585216);    //  8 MB  bf16 value
  float*          vsum  = (float*)(ws + 16973824);            //   4 KB
  unsigned short* S     = (unsigned short*)(ws + 16977920);   // 4 x 32 MB ordered-u16 S

  prep_kernel<<<4161, 256, 0, stream>>>(x, W, xn, norms, Wb, vsum);
  compute_kernel<<<4352, 256, 0, stream>>>(xn, norms, Wb, bias, value, vsum, S);
  select_kernel<<<BN_, 256, 0, stream>>>(S, value, vsum, out);
}

// Round 6
// 249.109 us; speedup vs baseline: 1.9542x; 1.1842x over previous
//
#include <hip/hip_runtime.h>
#include <hip/hip_bf16.h>
#include <stdint.h>

#define B_ 4
#define N_ 4096
#define D_ 256
#define K_ 64
#define BN_ (B_*N_)

typedef __attribute__((ext_vector_type(8))) short bf16x8;
typedef __attribute__((ext_vector_type(8))) unsigned short u16x8;
typedef __attribute__((ext_vector_type(4))) float f32x4;

static __device__ __forceinline__ unsigned short f2bf(float f) {
  union { float f; unsigned u; } x; x.f = f;
  unsigned r = x.u + 0x7fffu + ((x.u >> 16) & 1u);
  return (unsigned short)(r >> 16);
}
static __device__ __forceinline__ float bf2f(unsigned short u) {
  union { unsigned u; float f; } x; x.u = ((unsigned)u) << 16;
  return x.f;
}
static __device__ __forceinline__ f32x4 mfma16(bf16x8 a, bf16x8 b, f32x4 c) {
  return __builtin_amdgcn_mfma_f32_16x16x32_bf16(a, b, c, 0, 0, 0);
}

// ---------------- kernel 1: normalize rows + W->bf16 + vsum zero ----------------
__global__ __launch_bounds__(256) void prep_kernel(
    const float* __restrict__ x, const float* __restrict__ W,
    unsigned short* __restrict__ xn, float* __restrict__ norms,
    unsigned short* __restrict__ Wb, float* __restrict__ vsum) {
  const int bid = blockIdx.x;
  if (bid < 4096) {
    int row = bid * 4 + (threadIdx.x >> 6);
    int lane = threadIdx.x & 63;
    const float4 v = reinterpret_cast<const float4*>(x + (size_t)row * D_)[lane];
    float ss = v.x*v.x + v.y*v.y + v.z*v.z + v.w*v.w;
    #pragma unroll
    for (int off = 32; off > 0; off >>= 1) ss += __shfl_xor(ss, off);
    float nrm = sqrtf(ss);
    float scale = 1.0f / fmaxf(nrm, 1e-12f);
    ushort4 o;
    o.x = f2bf(v.x * scale); o.y = f2bf(v.y * scale);
    o.z = f2bf(v.z * scale); o.w = f2bf(v.w * scale);
    reinterpret_cast<ushort4*>(xn + (size_t)row * D_)[lane] = o;
    if (lane == 0) norms[row] = nrm;
  } else if (bid < 4160) {
    int i = (bid - 4096) * 256 + threadIdx.x;
    float4 v = reinterpret_cast<const float4*>(W)[i];
    ushort4 o; o.x = f2bf(v.x); o.y = f2bf(v.y); o.z = f2bf(v.z); o.w = f2bf(v.w);
    reinterpret_cast<ushort4*>(Wb)[i] = o;
  } else {
    reinterpret_cast<float4*>(vsum)[threadIdx.x] = (float4){0.f, 0.f, 0.f, 0.f};
  }
}

// ---------------- kernel 2: unified 128x128-tile GEMM ----------------
// blocks 0..255: value = (xn*norm) @ W^T + b  (bf16 out + vsum)
// blocks 256..4351: S = Xn @ Xn^T per batch, stored as ordered u16 keys.
// Both operands staged coalesced into XOR-swizzled LDS; swizzled-LDS bounce
// epilogue for 1KB-coalesced global stores.
__global__ __launch_bounds__(256, 3) void compute_kernel(
    const unsigned short* __restrict__ xn, const float* __restrict__ norms,
    const unsigned short* __restrict__ Wb, const float* __restrict__ bias,
    unsigned short* __restrict__ value, float* __restrict__ vsum,
    unsigned short* __restrict__ S) {
  __shared__ __attribute__((aligned(16))) unsigned char smem[33792];
  unsigned char* As = smem;                 // 16 KB swizzled A tile [128][64]
  unsigned char* Bs = smem + 16384;         // 16 KB swizzled B tile [128][64]
  float* ns_s   = (float*)(smem + 32768);   // [128] (value mode)
  float* bias_s = (float*)(smem + 33280);   // [128] (value mode)

  const int t = threadIdx.x, lane = t & 63, w = t >> 6;
  const int l15 = lane & 15, qv = lane >> 4, rb = qv * 4;
  const int wr = w >> 1, wc = w & 1;
  const int x7 = l15 & 7;

  const unsigned short* Asrc;
  const unsigned short* Bsrc;
  int rbG, cb, batch = 0;
  const bool vmode = (blockIdx.x < 256);
  if (vmode) {
    rbG = (blockIdx.x >> 1) * 128;          // global row block (0..16256)
    cb  = (blockIdx.x & 1) * 128;           // output col block (0 or 128)
    Asrc = xn + (size_t)rbG * D_;
    Bsrc = Wb + (size_t)cb * D_;
    if (t < 128) { ns_s[t] = norms[rbG + t]; bias_s[t] = bias[cb + t]; }
  } else {
    int g = blockIdx.x - 256;
    batch = g >> 10;
    int tl = g & 1023;
    rbG = (tl >> 5) * 128;                  // row block within batch
    cb  = (tl & 31) * 128;                  // col block within batch
    Asrc = xn + ((size_t)batch * N_ + rbG) * D_;
    Bsrc = xn + ((size_t)batch * N_ + cb)  * D_;
  }

  f32x4 acc[4][4];
  #pragma unroll
  for (int i = 0; i < 4; i++)
    #pragma unroll
    for (int j = 0; j < 4; j++) acc[i][j] = (f32x4){0.f,0.f,0.f,0.f};

  for (int kk = 0; kk < 4; kk++) {
    #pragma unroll
    for (int p = 0; p < 4; p++) {
      int q = t + p * 256;                  // 0..1023 chunk id
      int row = q >> 3, c = q & 7;
      int ld = row * 128 + ((c ^ (row & 7)) << 4);
      *(u16x8*)(As + ld) = *(const u16x8*)(Asrc + (size_t)row * D_ + kk * 64 + c * 8);
      *(u16x8*)(Bs + ld) = *(const u16x8*)(Bsrc + (size_t)row * D_ + kk * 64 + c * 8);
    }
    __syncthreads();
    #pragma unroll
    for (int ks = 0; ks < 2; ks++) {
      const int cpos = (((ks * 4 + qv) ^ x7) << 4);
      bf16x8 a[4], bb[4];
      #pragma unroll
      for (int rt = 0; rt < 4; rt++)
        a[rt] = *(const bf16x8*)(As + (wr*64 + rt*16 + l15) * 128 + cpos);
      #pragma unroll
      for (int ct = 0; ct < 4; ct++)
        bb[ct] = *(const bf16x8*)(Bs + (wc*64 + ct*16 + l15) * 128 + cpos);
      #pragma unroll
      for (int rt = 0; rt < 4; rt++)
        #pragma unroll
        for (int ct = 0; ct < 4; ct++)
          acc[rt][ct] = mfma16(a[rt], bb[ct], acc[rt][ct]);
    }
    __syncthreads();
  }

  // ---- epilogue via swizzled LDS bounce: kbuf[row][chunk^ (row&7)] ----
  unsigned short* kbuf = (unsigned short*)smem;   // [128][128] u16 = 32 KB
  if (vmode) {
    float vpart[4] = {0.f, 0.f, 0.f, 0.f};
    #pragma unroll
    for (int rt = 0; rt < 4; rt++)
      #pragma unroll
      for (int ct = 0; ct < 4; ct++) {
        int col_l = wc*64 + ct*16 + l15;
        int swc = ((col_l & 7) | ((((col_l >> 3)) << 3)));  // base; XOR applied per row below
        #pragma unroll
        for (int reg = 0; reg < 4; reg++) {
          int row_l = wr*64 + rt*16 + rb + reg;
          float v = acc[rt][ct][reg] * ns_s[row_l] + bias_s[col_l];
          int pos = (col_l & 7) | ((((col_l >> 3) ^ (row_l & 7))) << 3);
          kbuf[row_l * 128 + pos] = f2bf(v);
          vpart[ct] += v;
        }
        (void)swc;
      }
    int b2 = rbG >> 12;
    #pragma unroll
    for (int ct = 0; ct < 4; ct++)
      atomicAdd(&vsum[b2*D_ + cb + wc*64 + ct*16 + l15], vpart[ct]);
    __syncthreads();
    #pragma unroll
    for (int p = 0; p < 8; p++) {
      int q = t + p * 256;                  // 0..2047
      int row = q >> 4, c8 = q & 15;
      u16x8 d = *(const u16x8*)(kbuf + row * 128 + ((c8 ^ (row & 7)) << 3));
      *(u16x8*)(value + (size_t)(rbG + row) * D_ + cb + c8 * 8) = d;
    }
  } else {
    #pragma unroll
    for (int rt = 0; rt < 4; rt++)
      #pragma unroll
      for (int ct = 0; ct < 4; ct++) {
        int col_l = wc*64 + ct*16 + l15;
        #pragma unroll
        for (int reg = 0; reg < 4; reg++) {
          int row_l = wr*64 + rt*16 + rb + reg;
          unsigned short bits = f2bf(acc[rt][ct][reg]);
          unsigned short key = (bits & 0x8000u) ? (unsigned short)(~bits)
                                                : (unsigned short)(bits | 0x8000u);
          int pos = (col_l & 7) | ((((col_l >> 3) ^ (row_l & 7))) << 3);
          kbuf[row_l * 128 + pos] = key;
        }
      }
    __syncthreads();
    unsigned short* Sb = S + ((size_t)batch << 24);
    #pragma unroll
    for (int p = 0; p < 8; p++) {
      int q = t + p * 256;
      int row = q >> 4, c8 = q & 15;
      u16x8 d = *(const u16x8*)(kbuf + row * 128 + ((c8 ^ (row & 7)) << 3));
      *(u16x8*)(Sb + (size_t)(rbG + row) * N_ + cb + c8 * 8) = d;
    }
  }
}

// ---------------- kernel 3: per-row radix-select top-64 + sparse softmax @ V ----
// 2048-bin (key>>5) wave-private first pass (low atomic contention), 32-bin
// second pass on the remaining 5 bits. Exact ties by ticket.
__global__ __launch_bounds__(256, 4) void select_kernel(
    const unsigned short* __restrict__ S,
    const unsigned short* __restrict__ value,
    const float* __restrict__ vsum,
    float* __restrict__ out) {
  __shared__ __attribute__((aligned(16))) unsigned bb[4 * 2048];
  __shared__ unsigned wt4[4];
  __shared__ float zred[4];
  __shared__ int hb_s, cg_s, lb_s, cglo_s, nsel_s, neq_s;
  __shared__ int widx_s[64];
  __shared__ float wv_s[64];
  __shared__ float partial[4][256];

  const int t = threadIdx.x, lane = t & 63, w = t >> 6;
  const int b = blockIdx.x >> 12;
  const int r = blockIdx.x & 4095;
  const unsigned short* srow = S + ((size_t)b << 24) + ((size_t)r << 12);

  u16x8 va = *(const u16x8*)(srow + t*16);
  u16x8 vb2 = *(const u16x8*)(srow + t*16 + 8);
  unsigned ov[16];
  #pragma unroll
  for (int j = 0; j < 8; j++) { ov[j] = (unsigned short)va[j]; ov[j+8] = (unsigned short)vb2[j]; }

  #pragma unroll
  for (int p = 0; p < 8; p++)
    *(uint4*)&bb[(t + p*256)*4] = (uint4){0u,0u,0u,0u};
  if (t == 0) { nsel_s = 0; neq_s = 0; }
  __syncthreads();                                          // B0
  #pragma unroll
  for (int j = 0; j < 16; j++) atomicAdd(&bb[w*2048 + (ov[j] >> 5)], 1u);
  __syncthreads();                                          // B1
  // thread t owns bins 8t..8t+7
  unsigned cnt[8];
  #pragma unroll
  for (int j = 0; j < 8; j++) cnt[j] = 0;
  #pragma unroll
  for (int ww = 0; ww < 4; ww++) {
    uint4 c0 = *(const uint4*)&bb[ww*2048 + t*8];
    uint4 c1 = *(const uint4*)&bb[ww*2048 + t*8 + 4];
    cnt[0]+=c0.x; cnt[1]+=c0.y; cnt[2]+=c0.z; cnt[3]+=c0.w;
    cnt[4]+=c1.x; cnt[5]+=c1.y; cnt[6]+=c1.z; cnt[7]+=c1.w;
  }
  unsigned own = cnt[0]+cnt[1]+cnt[2]+cnt[3]+cnt[4]+cnt[5]+cnt[6]+cnt[7];
  unsigned v = own;
  #pragma unroll
  for (int off = 1; off < 64; off <<= 1) {
    unsigned o = __shfl_down(v, off);
    if (lane + off < 64) v += o;
  }
  if (lane == 0) wt4[w] = v;
  __syncthreads();                                          // B2
  unsigned sfx = v;
  #pragma unroll
  for (int ww = 0; ww < 4; ww++) if (ww > w) sfx += wt4[ww];
  unsigned nxt = sfx - own;
  if (sfx >= 64u && nxt < 64u) {
    unsigned c = nxt;
    #pragma unroll
    for (int jj = 7; jj >= 0; jj--) {
      unsigned cn = c + cnt[jj];
      if (cn >= 64u && c < 64u) { hb_s = t*8 + jj; cg_s = (int)c; }
      c = cn;
    }
  }
  if (t < 128) bb[(t >> 5)*2048 + (t & 31)] = 0;            // zero pass-2 bins
  __syncthreads();                                          // B3
  const unsigned hb = (unsigned)hb_s;
  const unsigned need2 = (unsigned)(64 - cg_s);             // >= 1 guaranteed
  #pragma unroll
  for (int j = 0; j < 16; j++)
    if ((ov[j] >> 5) == hb) atomicAdd(&bb[w*2048 + (ov[j] & 31u)], 1u);
  __syncthreads();                                          // B4
  if (w == 0) {
    unsigned own2 = 0;
    if (lane < 32)
      own2 = bb[lane] + bb[2048 + lane] + bb[4096 + lane] + bb[6144 + lane];
    unsigned v2 = own2;
    #pragma unroll
    for (int off = 1; off < 64; off <<= 1) {
      unsigned o = __shfl_down(v2, off);
      if (lane + off < 64) v2 += o;
    }
    unsigned nxt2 = v2 - own2;
    if (lane < 32 && v2 >= need2 && nxt2 < need2) { lb_s = lane; cglo_s = (int)nxt2; }
  }
  __syncthreads();                                          // B5
  const unsigned tau = (hb << 5) | (unsigned)lb_s;
  const int needeq = (int)need2 - cglo_s;                   // >= 1 guaranteed

  float zloc = 0.f;
  #pragma unroll
  for (int j = 0; j < 16; j++) {
    unsigned u = ov[j];
    bool take = (u > tau);
    if (!take && u == tau) { int k = atomicAdd(&neq_s, 1); take = (k < needeq); }
    if (take) {
      int slot = atomicAdd(&nsel_s, 1);
      unsigned short bits = (u & 0x8000u) ? (unsigned short)(u & 0x7FFFu)
                                          : (unsigned short)(~u);
      float s = bf2f(bits);
      float e = __expf(s);
      zloc += e;
      widx_s[slot] = t*16 + j;
      wv_s[slot] = e - 1.0f;
    }
  }
  #pragma unroll
  for (int off = 32; off > 0; off >>= 1) zloc += __shfl_xor(zloc, off);
  if (lane == 0) zred[w] = zloc;
  __syncthreads();                                          // B6
  const float Z = zred[0] + zred[1] + zred[2] + zred[3] + (float)(N_ - K_);

  const size_t vbase = (size_t)b << 20;   // b*N*D
  float ax = 0.f, ay = 0.f, az = 0.f, aw = 0.f;
  #pragma unroll
  for (int i = 0; i < 16; i++) {
    int sel = w*16 + i;
    int idx = widx_s[sel];
    float wt = wv_s[sel];
    ushort4 vv = *reinterpret_cast<const ushort4*>(&value[vbase + (size_t)idx*D_ + lane*4]);
    ax += wt * bf2f(vv.x);
    ay += wt * bf2f(vv.y);
    az += wt * bf2f(vv.z);
    aw += wt * bf2f(vv.w);
  }
  partial[w][lane*4 + 0] = ax;
  partial[w][lane*4 + 1] = ay;
  partial[w][lane*4 + 2] = az;
  partial[w][lane*4 + 3] = aw;
  __syncthreads();                                          // B7
  float ps = partial[0][t] + partial[1][t] + partial[2][t] + partial[3][t];
  out[(((size_t)b << 12) + r) * D_ + t] = (ps + vsum[b*D_ + t]) * (1.0f / Z);
}

extern "C" void kernel_launch(void* const* d_in, const int* in_sizes, int n_in,
                              void* d_out, int out_size, void* d_ws, size_t ws_size,
                              hipStream_t stream) {
  const float* x    = (const float*)d_in[0];
  const float* W    = (const float*)d_in[1];
  const float* bias = (const float*)d_in[2];
  float* out = (float*)d_out;
  char* ws = (char*)d_ws;
  unsigned short* xn    = (unsigned short*)(ws);              //  8 MB  bf16 normed x
  unsigned short* Wb    = (unsigned short*)(ws + 8388608);    // 128 KB bf16 W
  float*          norms = (float*)(ws + 8519680);             //  64 KB
  unsigned short* value = (unsigned short*)(ws + 8585216);    //  8 MB  bf16 value
  float*          vsum  = (float*)(ws + 16973824);            //   4 KB
  unsigned short* S     = (unsigned short*)(ws + 16977920);   // 4 x 32 MB ordered-u16 S

  prep_kernel<<<4161, 256, 0, stream>>>(x, W, xn, norms, Wb, vsum);
  compute_kernel<<<4352, 256, 0, stream>>>(xn, norms, Wb, bias, value, vsum, S);
  select_kernel<<<BN_, 256, 0, stream>>>(S, value, vsum, out);
}

// Round 7
// 222.042 us; speedup vs baseline: 2.1924x; 1.1219x over previous
//
#include <hip/hip_runtime.h>
#include <hip/hip_bf16.h>
#include <stdint.h>

#define B_ 4
#define N_ 4096
#define D_ 256
#define K_ 64
#define BN_ (B_*N_)

typedef __attribute__((ext_vector_type(8))) short bf16x8;
typedef __attribute__((ext_vector_type(8))) unsigned short u16x8;
typedef __attribute__((ext_vector_type(4))) float f32x4;
typedef __attribute__((address_space(1))) const unsigned int gas_u32;
typedef __attribute__((address_space(3))) unsigned int las_u32;

static __device__ __forceinline__ unsigned short f2bf(float f) {
  union { float f; unsigned u; } x; x.f = f;
  unsigned r = x.u + 0x7fffu + ((x.u >> 16) & 1u);
  return (unsigned short)(r >> 16);
}
static __device__ __forceinline__ float bf2f(unsigned short u) {
  union { unsigned u; float f; } x; x.u = ((unsigned)u) << 16;
  return x.f;
}
static __device__ __forceinline__ f32x4 mfma16(bf16x8 a, bf16x8 b, f32x4 c) {
  return __builtin_amdgcn_mfma_f32_16x16x32_bf16(a, b, c, 0, 0, 0);
}

// ---------------- kernel 1: normalize rows + W->bf16 + vsum zero ----------------
__global__ __launch_bounds__(256) void prep_kernel(
    const float* __restrict__ x, const float* __restrict__ W,
    unsigned short* __restrict__ xn, float* __restrict__ norms,
    unsigned short* __restrict__ Wb, float* __restrict__ vsum) {
  const int bid = blockIdx.x;
  if (bid < 4096) {
    int row = bid * 4 + (threadIdx.x >> 6);
    int lane = threadIdx.x & 63;
    const float4 v = reinterpret_cast<const float4*>(x + (size_t)row * D_)[lane];
    float ss = v.x*v.x + v.y*v.y + v.z*v.z + v.w*v.w;
    #pragma unroll
    for (int off = 32; off > 0; off >>= 1) ss += __shfl_xor(ss, off);
    float nrm = sqrtf(ss);
    float scale = 1.0f / fmaxf(nrm, 1e-12f);
    ushort4 o;
    o.x = f2bf(v.x * scale); o.y = f2bf(v.y * scale);
    o.z = f2bf(v.z * scale); o.w = f2bf(v.w * scale);
    reinterpret_cast<ushort4*>(xn + (size_t)row * D_)[lane] = o;
    if (lane == 0) norms[row] = nrm;
  } else if (bid < 4160) {
    int i = (bid - 4096) * 256 + threadIdx.x;
    float4 v = reinterpret_cast<const float4*>(W)[i];
    ushort4 o; o.x = f2bf(v.x); o.y = f2bf(v.y); o.z = f2bf(v.z); o.w = f2bf(v.w);
    reinterpret_cast<ushort4*>(Wb)[i] = o;
  } else {
    reinterpret_cast<float4*>(vsum)[threadIdx.x] = (float4){0.f, 0.f, 0.f, 0.f};
  }
}

// ---------------- kernel 2: unified 128x128-tile GEMM ----------------
// blocks 0..255: value = (xn*norm) @ W^T + b  (bf16 out + vsum)
// blocks 256..4351: S = Xn @ Xn^T per batch, stored as ordered u16 keys.
// Staging via global_load_lds width=16: linear LDS dest + pre-swizzled global
// source (involution c ^= row&7 within each 128B row segment -> coalesced).
__global__ __launch_bounds__(256, 3) void compute_kernel(
    const unsigned short* __restrict__ xn, const float* __restrict__ norms,
    const unsigned short* __restrict__ Wb, const float* __restrict__ bias,
    unsigned short* __restrict__ value, float* __restrict__ vsum,
    unsigned short* __restrict__ S) {
  __shared__ __attribute__((aligned(16))) unsigned char smem[33792];
  unsigned char* As = smem;                 // 16 KB swizzled A tile [128][64]
  unsigned char* Bs = smem + 16384;         // 16 KB swizzled B tile [128][64]
  float* ns_s   = (float*)(smem + 32768);   // [128] (value mode)
  float* bias_s = (float*)(smem + 33280);   // [128] (value mode)

  const int t = threadIdx.x, lane = t & 63, w = t >> 6;
  const int l15 = lane & 15, qv = lane >> 4, rb = qv * 4;
  const int wr = w >> 1, wc = w & 1;
  const int x7 = l15 & 7;

  const unsigned short* Asrc;
  const unsigned short* Bsrc;
  int rbG, cb, batch = 0;
  const bool vmode = (blockIdx.x < 256);
  if (vmode) {
    rbG = (blockIdx.x >> 1) * 128;
    cb  = (blockIdx.x & 1) * 128;
    Asrc = xn + (size_t)rbG * D_;
    Bsrc = Wb + (size_t)cb * D_;
    if (t < 128) { ns_s[t] = norms[rbG + t]; bias_s[t] = bias[cb + t]; }
  } else {
    int g = blockIdx.x - 256;
    batch = g >> 10;
    int tl = g & 1023;
    rbG = (tl >> 5) * 128;
    cb  = (tl & 31) * 128;
    Asrc = xn + ((size_t)batch * N_ + rbG) * D_;
    Bsrc = xn + ((size_t)batch * N_ + cb)  * D_;
  }

  // precompute this thread's 4 staging (row, swizzled-chunk) pairs
  f32x4 acc[4][4];
  #pragma unroll
  for (int i = 0; i < 4; i++)
    #pragma unroll
    for (int j = 0; j < 4; j++) acc[i][j] = (f32x4){0.f,0.f,0.f,0.f};

  for (int kk = 0; kk < 4; kk++) {
    #pragma unroll
    for (int p = 0; p < 4; p++) {
      int q = t + p * 256;                  // 0..1023
      int row = q >> 3, c = q & 7;
      int cg = (c ^ (row & 7)) * 8;         // pre-swizzled source chunk (elems)
      __builtin_amdgcn_global_load_lds(
          (gas_u32*)(Asrc + (size_t)row * D_ + kk * 64 + cg),
          (las_u32*)(As + q * 16), 16, 0, 0);
      __builtin_amdgcn_global_load_lds(
          (gas_u32*)(Bsrc + (size_t)row * D_ + kk * 64 + cg),
          (las_u32*)(Bs + q * 16), 16, 0, 0);
    }
    __syncthreads();
    #pragma unroll
    for (int ks = 0; ks < 2; ks++) {
      const int cpos = (((ks * 4 + qv) ^ x7) << 4);
      bf16x8 a[4], bb[4];
      #pragma unroll
      for (int rt = 0; rt < 4; rt++)
        a[rt] = *(const bf16x8*)(As + (wr*64 + rt*16 + l15) * 128 + cpos);
      #pragma unroll
      for (int ct = 0; ct < 4; ct++)
        bb[ct] = *(const bf16x8*)(Bs + (wc*64 + ct*16 + l15) * 128 + cpos);
      #pragma unroll
      for (int rt = 0; rt < 4; rt++)
        #pragma unroll
        for (int ct = 0; ct < 4; ct++)
          acc[rt][ct] = mfma16(a[rt], bb[ct], acc[rt][ct]);
    }
    __syncthreads();
  }

  // ---- epilogue via swizzled LDS bounce over As/Bs region ----
  unsigned short* kbuf = (unsigned short*)smem;   // [128][128] u16 = 32 KB
  if (vmode) {
    float vpart[4] = {0.f, 0.f, 0.f, 0.f};
    #pragma unroll
    for (int rt = 0; rt < 4; rt++)
      #pragma unroll
      for (int ct = 0; ct < 4; ct++) {
        int col_l = wc*64 + ct*16 + l15;
        #pragma unroll
        for (int reg = 0; reg < 4; reg++) {
          int row_l = wr*64 + rt*16 + rb + reg;
          float v = acc[rt][ct][reg] * ns_s[row_l] + bias_s[col_l];
          int pos = (col_l & 7) | ((((col_l >> 3) ^ (row_l & 7))) << 3);
          kbuf[row_l * 128 + pos] = f2bf(v);
          vpart[ct] += v;
        }
      }
    int b2 = rbG >> 12;
    #pragma unroll
    for (int ct = 0; ct < 4; ct++)
      atomicAdd(&vsum[b2*D_ + cb + wc*64 + ct*16 + l15], vpart[ct]);
    __syncthreads();
    #pragma unroll
    for (int p = 0; p < 8; p++) {
      int q = t + p * 256;
      int row = q >> 4, c8 = q & 15;
      u16x8 d = *(const u16x8*)(kbuf + row * 128 + ((c8 ^ (row & 7)) << 3));
      *(u16x8*)(value + (size_t)(rbG + row) * D_ + cb + c8 * 8) = d;
    }
  } else {
    #pragma unroll
    for (int rt = 0; rt < 4; rt++)
      #pragma unroll
      for (int ct = 0; ct < 4; ct++) {
        int col_l = wc*64 + ct*16 + l15;
        #pragma unroll
        for (int reg = 0; reg < 4; reg++) {
          int row_l = wr*64 + rt*16 + rb + reg;
          unsigned short bits = f2bf(acc[rt][ct][reg]);
          unsigned short key = (bits & 0x8000u) ? (unsigned short)(~bits)
                                                : (unsigned short)(bits | 0x8000u);
          int pos = (col_l & 7) | ((((col_l >> 3) ^ (row_l & 7))) << 3);
          kbuf[row_l * 128 + pos] = key;
        }
      }
    __syncthreads();
    unsigned short* Sb = S + ((size_t)batch << 24);
    #pragma unroll
    for (int p = 0; p < 8; p++) {
      int q = t + p * 256;
      int row = q >> 4, c8 = q & 15;
      u16x8 d = *(const u16x8*)(kbuf + row * 128 + ((c8 ^ (row & 7)) << 3));
      *(u16x8*)(Sb + (size_t)(rbG + row) * N_ + cb + c8 * 8) = d;
    }
  }
}

// ---------------- kernel 3: per-row radix-select top-64 + sparse softmax @ V ----
// 2048-bin (key>>5) first pass with TWO shared copies (waves 0-1 / 2-3), 32-bin
// second pass. partial[] overlays the bins region -> ~17 KB LDS, 8 blocks/CU.
__global__ __launch_bounds__(256, 8) void select_kernel(
    const unsigned short* __restrict__ S,
    const unsigned short* __restrict__ value,
    const float* __restrict__ vsum,
    float* __restrict__ out) {
  __shared__ __attribute__((aligned(16))) unsigned bb2[2][2048];   // 16 KB
  __shared__ unsigned wt4[4];
  __shared__ float zred[4];
  __shared__ int hb_s, cg_s, lb_s, cglo_s, nsel_s, neq_s;
  __shared__ int widx_s[64];
  __shared__ float wv_s[64];
  float* partial = (float*)bb2;   // overlay: used only after bins are dead

  const int t = threadIdx.x, lane = t & 63, w = t >> 6;
  const int cp = w >> 1;
  const int b = blockIdx.x >> 12;
  const int r = blockIdx.x & 4095;
  const unsigned short* srow = S + ((size_t)b << 24) + ((size_t)r << 12);

  u16x8 va = *(const u16x8*)(srow + t*16);
  u16x8 vb2 = *(const u16x8*)(srow + t*16 + 8);
  unsigned ov[16];
  #pragma unroll
  for (int j = 0; j < 8; j++) { ov[j] = (unsigned short)va[j]; ov[j+8] = (unsigned short)vb2[j]; }

  #pragma unroll
  for (int p = 0; p < 4; p++)
    *(uint4*)&bb2[0][(t + p*256)*4] = (uint4){0u,0u,0u,0u};
  if (t == 0) { nsel_s = 0; neq_s = 0; }
  __syncthreads();                                          // B0
  #pragma unroll
  for (int j = 0; j < 16; j++) atomicAdd(&bb2[cp][ov[j] >> 5], 1u);
  __syncthreads();                                          // B1
  // thread t owns bins 8t..8t+7
  unsigned cnt[8];
  {
    uint4 c0 = *(const uint4*)&bb2[0][t*8];
    uint4 c1 = *(const uint4*)&bb2[0][t*8 + 4];
    uint4 d0 = *(const uint4*)&bb2[1][t*8];
    uint4 d1 = *(const uint4*)&bb2[1][t*8 + 4];
    cnt[0]=c0.x+d0.x; cnt[1]=c0.y+d0.y; cnt[2]=c0.z+d0.z; cnt[3]=c0.w+d0.w;
    cnt[4]=c1.x+d1.x; cnt[5]=c1.y+d1.y; cnt[6]=c1.z+d1.z; cnt[7]=c1.w+d1.w;
  }
  unsigned own = cnt[0]+cnt[1]+cnt[2]+cnt[3]+cnt[4]+cnt[5]+cnt[6]+cnt[7];
  unsigned v = own;
  #pragma unroll
  for (int off = 1; off < 64; off <<= 1) {
    unsigned o = __shfl_down(v, off);
    if (lane + off < 64) v += o;
  }
  if (lane == 0) wt4[w] = v;
  __syncthreads();                                          // B2
  unsigned sfx = v;
  #pragma unroll
  for (int ww = 0; ww < 4; ww++) if (ww > w) sfx += wt4[ww];
  unsigned nxt = sfx - own;
  if (sfx >= 64u && nxt < 64u) {
    unsigned c = nxt;
    #pragma unroll
    for (int jj = 7; jj >= 0; jj--) {
      unsigned cn = c + cnt[jj];
      if (cn >= 64u && c < 64u) { hb_s = t*8 + jj; cg_s = (int)c; }
      c = cn;
    }
  }
  if (t < 64) bb2[t >> 5][t & 31] = 0;                      // zero pass-2 bins
  __syncthreads();                                          // B3
  const unsigned hb = (unsigned)hb_s;
  const unsigned need2 = (unsigned)(64 - cg_s);             // >= 1 guaranteed
  #pragma unroll
  for (int j = 0; j < 16; j++)
    if ((ov[j] >> 5) == hb) atomicAdd(&bb2[cp][ov[j] & 31u], 1u);
  __syncthreads();                                          // B4
  if (w == 0) {
    unsigned own2 = 0;
    if (lane < 32) own2 = bb2[0][lane] + bb2[1][lane];
    unsigned v2 = own2;
    #pragma unroll
    for (int off = 1; off < 64; off <<= 1) {
      unsigned o = __shfl_down(v2, off);
      if (lane + off < 64) v2 += o;
    }
    unsigned nxt2 = v2 - own2;
    if (lane < 32 && v2 >= need2 && nxt2 < need2) { lb_s = lane; cglo_s = (int)nxt2; }
  }
  __syncthreads();                                          // B5
  const unsigned tau = (hb << 5) | (unsigned)lb_s;
  const int needeq = (int)need2 - cglo_s;                   // >= 1 guaranteed

  float zloc = 0.f;
  #pragma unroll
  for (int j = 0; j < 16; j++) {
    unsigned u = ov[j];
    bool take = (u > tau);
    if (!take && u == tau) { int k = atomicAdd(&neq_s, 1); take = (k < needeq); }
    if (take) {
      int slot = atomicAdd(&nsel_s, 1);
      unsigned short bits = (u & 0x8000u) ? (unsigned short)(u & 0x7FFFu)
                                          : (unsigned short)(~u);
      float s = bf2f(bits);
      float e = __expf(s);
      zloc += e;
      widx_s[slot] = t*16 + j;
      wv_s[slot] = e - 1.0f;
    }
  }
  #pragma unroll
  for (int off = 32; off > 0; off >>= 1) zloc += __shfl_xor(zloc, off);
  if (lane == 0) zred[w] = zloc;
  __syncthreads();                                          // B6
  const float Z = zred[0] + zred[1] + zred[2] + zred[3] + (float)(N_ - K_);

  const size_t vbase = (size_t)b << 20;   // b*N*D
  float ax = 0.f, ay = 0.f, az = 0.f, aw = 0.f;
  #pragma unroll
  for (int i = 0; i < 16; i++) {
    int sel = w*16 + i;
    int idx = widx_s[sel];
    float wt = wv_s[sel];
    ushort4 vv = *reinterpret_cast<const ushort4*>(&value[vbase + (size_t)idx*D_ + lane*4]);
    ax += wt * bf2f(vv.x);
    ay += wt * bf2f(vv.y);
    az += wt * bf2f(vv.z);
    aw += wt * bf2f(vv.w);
  }
  partial[w*256 + lane*4 + 0] = ax;
  partial[w*256 + lane*4 + 1] = ay;
  partial[w*256 + lane*4 + 2] = az;
  partial[w*256 + lane*4 + 3] = aw;
  __syncthreads();                                          // B7
  float ps = partial[t] + partial[256 + t] + partial[512 + t] + partial[768 + t];
  out[(((size_t)b << 12) + r) * D_ + t] = (ps + vsum[b*D_ + t]) * (1.0f / Z);
}

extern "C" void kernel_launch(void* const* d_in, const int* in_sizes, int n_in,
                              void* d_out, int out_size, void* d_ws, size_t ws_size,
                              hipStream_t stream) {
  const float* x    = (const float*)d_in[0];
  const float* W    = (const float*)d_in[1];
  const float* bias = (const float*)d_in[2];
  float* out = (float*)d_out;
  char* ws = (char*)d_ws;
  unsigned short* xn    = (unsigned short*)(ws);              //  8 MB  bf16 normed x
  unsigned short* Wb    = (unsigned short*)(ws + 8388608);    // 128 KB bf16 W
  float*          norms = (float*)(ws + 8519680);             //  64 KB
  unsigned short* value = (unsigned short*)(ws + 8585216);    //  8 MB  bf16 value
  float*          vsum  = (float*)(ws + 16973824);            //   4 KB
  unsigned short* S     = (unsigned short*)(ws + 16977920);   // 4 x 32 MB ordered-u16 S

  prep_kernel<<<4161, 256, 0, stream>>>(x, W, xn, norms, Wb, vsum);
  compute_kernel<<<4352, 256, 0, stream>>>(xn, norms, Wb, bias, value, vsum, S);
  select_kernel<<<BN_, 256, 0, stream>>>(S, value, vsum, out);
}

// Round 8
// 211.721 us; speedup vs baseline: 2.2993x; 1.0487x over previous
//
#include <hip/hip_runtime.h>
#include <hip/hip_bf16.h>
#include <stdint.h>

#define B_ 4
#define N_ 4096
#define D_ 256
#define K_ 64
#define BN_ (B_*N_)

typedef __attribute__((ext_vector_type(8))) short bf16x8;
typedef __attribute__((ext_vector_type(8))) unsigned short u16x8;
typedef __attribute__((ext_vector_type(4))) float f32x4;
typedef __attribute__((address_space(1))) const unsigned int gas_u32;
typedef __attribute__((address_space(3))) unsigned int las_u32;

static __device__ __forceinline__ unsigned short f2bf(float f) {
  union { float f; unsigned u; } x; x.f = f;
  unsigned r = x.u + 0x7fffu + ((x.u >> 16) & 1u);
  return (unsigned short)(r >> 16);
}
static __device__ __forceinline__ float bf2f(unsigned short u) {
  union { unsigned u; float f; } x; x.u = ((unsigned)u) << 16;
  return x.f;
}
static __device__ __forceinline__ f32x4 mfma16(bf16x8 a, bf16x8 b, f32x4 c) {
  return __builtin_amdgcn_mfma_f32_16x16x32_bf16(a, b, c, 0, 0, 0);
}

// ---------------- kernel 1: normalize rows + W->bf16 + vsum zero ----------------
__global__ __launch_bounds__(256) void prep_kernel(
    const float* __restrict__ x, const float* __restrict__ W,
    unsigned short* __restrict__ xn, float* __restrict__ norms,
    unsigned short* __restrict__ Wb, float* __restrict__ vsum) {
  const int bid = blockIdx.x;
  if (bid < 4096) {
    int row = bid * 4 + (threadIdx.x >> 6);
    int lane = threadIdx.x & 63;
    const float4 v = reinterpret_cast<const float4*>(x + (size_t)row * D_)[lane];
    float ss = v.x*v.x + v.y*v.y + v.z*v.z + v.w*v.w;
    #pragma unroll
    for (int off = 32; off > 0; off >>= 1) ss += __shfl_xor(ss, off);
    float nrm = sqrtf(ss);
    float scale = 1.0f / fmaxf(nrm, 1e-12f);
    ushort4 o;
    o.x = f2bf(v.x * scale); o.y = f2bf(v.y * scale);
    o.z = f2bf(v.z * scale); o.w = f2bf(v.w * scale);
    reinterpret_cast<ushort4*>(xn + (size_t)row * D_)[lane] = o;
    if (lane == 0) norms[row] = nrm;
  } else if (bid < 4160) {
    int i = (bid - 4096) * 256 + threadIdx.x;
    float4 v = reinterpret_cast<const float4*>(W)[i];
    ushort4 o; o.x = f2bf(v.x); o.y = f2bf(v.y); o.z = f2bf(v.z); o.w = f2bf(v.w);
    reinterpret_cast<ushort4*>(Wb)[i] = o;
  } else {
    reinterpret_cast<float4*>(vsum)[threadIdx.x] = (float4){0.f, 0.f, 0.f, 0.f};
  }
}

// ---------------- kernel 2: unified 128x128-tile GEMM, pipelined ----------------
// Per K-step: ds_read ALL frags -> barrier -> issue next global_load_lds ->
// MFMA (regs only, overlaps load flight) -> barrier (drains vmcnt).
__global__ __launch_bounds__(256, 3) void compute_kernel(
    const unsigned short* __restrict__ xn, const float* __restrict__ norms,
    const unsigned short* __restrict__ Wb, const float* __restrict__ bias,
    unsigned short* __restrict__ value, float* __restrict__ vsum,
    unsigned short* __restrict__ S) {
  __shared__ __attribute__((aligned(16))) unsigned char smem[33792];
  unsigned char* As = smem;                 // 16 KB swizzled A tile [128][64]
  unsigned char* Bs = smem + 16384;         // 16 KB swizzled B tile [128][64]
  float* ns_s   = (float*)(smem + 32768);   // [128] (value mode)
  float* bias_s = (float*)(smem + 33280);   // [128] (value mode)

  const int t = threadIdx.x, lane = t & 63, w = t >> 6;
  const int l15 = lane & 15, qv = lane >> 4, rb = qv * 4;
  const int wr = w >> 1, wc = w & 1;
  const int x7 = l15 & 7;

  const unsigned short* Asrc;
  const unsigned short* Bsrc;
  int rbG, cb, batch = 0;
  const bool vmode = (blockIdx.x < 256);
  if (vmode) {
    rbG = (blockIdx.x >> 1) * 128;
    cb  = (blockIdx.x & 1) * 128;
    Asrc = xn + (size_t)rbG * D_;
    Bsrc = Wb + (size_t)cb * D_;
    if (t < 128) { ns_s[t] = norms[rbG + t]; bias_s[t] = bias[cb + t]; }
  } else {
    int g = blockIdx.x - 256;
    batch = g >> 10;
    int tl = g & 1023;
    rbG = (tl >> 5) * 128;
    cb  = (tl & 31) * 128;
    Asrc = xn + ((size_t)batch * N_ + rbG) * D_;
    Bsrc = xn + ((size_t)batch * N_ + cb)  * D_;
  }

  auto STAGE = [&](int kk) {
    #pragma unroll
    for (int p = 0; p < 4; p++) {
      int q = t + p * 256;                  // 0..1023
      int row = q >> 3, c = q & 7;
      int cg = (c ^ (row & 7)) * 8;         // pre-swizzled source chunk (elems)
      __builtin_amdgcn_global_load_lds(
          (gas_u32*)(Asrc + (size_t)row * D_ + kk * 64 + cg),
          (las_u32*)(As + q * 16), 16, 0, 0);
      __builtin_amdgcn_global_load_lds(
          (gas_u32*)(Bsrc + (size_t)row * D_ + kk * 64 + cg),
          (las_u32*)(Bs + q * 16), 16, 0, 0);
    }
  };

  f32x4 acc[4][4];
  #pragma unroll
  for (int i = 0; i < 4; i++)
    #pragma unroll
    for (int j = 0; j < 4; j++) acc[i][j] = (f32x4){0.f,0.f,0.f,0.f};

  STAGE(0);
  __syncthreads();
  for (int kk = 0; kk < 4; kk++) {
    bf16x8 afr[2][4], bfr[2][4];
    #pragma unroll
    for (int ks = 0; ks < 2; ks++) {
      const int cpos = (((ks * 4 + qv) ^ x7) << 4);
      #pragma unroll
      for (int rt = 0; rt < 4; rt++)
        afr[ks][rt] = *(const bf16x8*)(As + (wr*64 + rt*16 + l15) * 128 + cpos);
      #pragma unroll
      for (int ct = 0; ct < 4; ct++)
        bfr[ks][ct] = *(const bf16x8*)(Bs + (wc*64 + ct*16 + l15) * 128 + cpos);
    }
    __syncthreads();                        // all waves' frag reads retired
    if (kk < 3) STAGE(kk + 1);              // overwrite tile; MFMA hides flight
    #pragma unroll
    for (int ks = 0; ks < 2; ks++)
      #pragma unroll
      for (int rt = 0; rt < 4; rt++)
        #pragma unroll
        for (int ct = 0; ct < 4; ct++)
          acc[rt][ct] = mfma16(afr[ks][rt], bfr[ks][ct], acc[rt][ct]);
    if (kk < 3) __syncthreads();            // drains vmcnt(0): stage landed
  }

  // ---- epilogue via swizzled LDS bounce over As/Bs region ----
  unsigned short* kbuf = (unsigned short*)smem;   // [128][128] u16 = 32 KB
  if (vmode) {
    float vpart[4] = {0.f, 0.f, 0.f, 0.f};
    #pragma unroll
    for (int rt = 0; rt < 4; rt++)
      #pragma unroll
      for (int ct = 0; ct < 4; ct++) {
        int col_l = wc*64 + ct*16 + l15;
        #pragma unroll
        for (int reg = 0; reg < 4; reg++) {
          int row_l = wr*64 + rt*16 + rb + reg;
          float v = acc[rt][ct][reg] * ns_s[row_l] + bias_s[col_l];
          int pos = (col_l & 7) | ((((col_l >> 3) ^ (row_l & 7))) << 3);
          kbuf[row_l * 128 + pos] = f2bf(v);
          vpart[ct] += v;
        }
      }
    int b2 = rbG >> 12;
    #pragma unroll
    for (int ct = 0; ct < 4; ct++)
      atomicAdd(&vsum[b2*D_ + cb + wc*64 + ct*16 + l15], vpart[ct]);
    __syncthreads();
    #pragma unroll
    for (int p = 0; p < 8; p++) {
      int q = t + p * 256;
      int row = q >> 4, c8 = q & 15;
      u16x8 d = *(const u16x8*)(kbuf + row * 128 + ((c8 ^ (row & 7)) << 3));
      *(u16x8*)(value + (size_t)(rbG + row) * D_ + cb + c8 * 8) = d;
    }
  } else {
    #pragma unroll
    for (int rt = 0; rt < 4; rt++)
      #pragma unroll
      for (int ct = 0; ct < 4; ct++) {
        int col_l = wc*64 + ct*16 + l15;
        #pragma unroll
        for (int reg = 0; reg < 4; reg++) {
          int row_l = wr*64 + rt*16 + rb + reg;
          unsigned short bits = f2bf(acc[rt][ct][reg]);
          unsigned short key = (bits & 0x8000u) ? (unsigned short)(~bits)
                                                : (unsigned short)(bits | 0x8000u);
          int pos = (col_l & 7) | ((((col_l >> 3) ^ (row_l & 7))) << 3);
          kbuf[row_l * 128 + pos] = key;
        }
      }
    __syncthreads();
    unsigned short* Sb = S + ((size_t)batch << 24);
    #pragma unroll
    for (int p = 0; p < 8; p++) {
      int q = t + p * 256;
      int row = q >> 4, c8 = q & 15;
      u16x8 d = *(const u16x8*)(kbuf + row * 128 + ((c8 ^ (row & 7)) << 3));
      *(u16x8*)(Sb + (size_t)(rbG + row) * N_ + cb + c8 * 8) = d;
    }
  }
}

// ---------------- kernel 3: wave-per-row top-64 + sparse softmax @ V ----------
// 4 rows/block, one 64-lane wave per row, ZERO barriers. 2048-bin histogram
// packed as u16 pairs in 1024 u32 words (counts <= 4096: no carry), wave-local
// atomics, shfl suffix scans, pack+max broadcasts. Exact ties by ticket.
__global__ __launch_bounds__(256) void select_kernel(
    const unsigned short* __restrict__ S,
    const unsigned short* __restrict__ value,
    const float* __restrict__ vsum,
    float* __restrict__ out) {
  __shared__ unsigned hist[4][1024];      // 16 KB: per-wave packed bins
  __shared__ unsigned pair2[4][64][2];    //  2 KB: (byte-offset, weight bits)
  __shared__ int cnts[4][2];              // nsel, neq per wave

  const int t = threadIdx.x, lane = t & 63, w = t >> 6;
  const int rowg = blockIdx.x * 4 + w;
  const int b = rowg >> 12;
  const int r = rowg & 4095;
  const unsigned short* srow = S + ((size_t)b << 24) + ((size_t)r << 12);

  // load the row's 4096 keys: 64 keys/lane as 8 x 16B (coalesced)
  uint4 kq[8];
  #pragma unroll
  for (int c = 0; c < 8; c++)
    kq[c] = *(const uint4*)(srow + c*512 + lane*8);

  // zero this wave's bins (wave-local, DS pipe is in-order per wave)
  #pragma unroll
  for (int p = 0; p < 4; p++)
    *(uint4*)&hist[w][lane*16 + p*4] = (uint4){0u,0u,0u,0u};
  if (lane == 0) { cnts[w][0] = 0; cnts[w][1] = 0; }

  // pass 1: 2048-bin histogram (bin = key>>5), packed halves
  #pragma unroll
  for (int c = 0; c < 8; c++) {
    unsigned uu[4] = {kq[c].x, kq[c].y, kq[c].z, kq[c].w};
    #pragma unroll
    for (int m = 0; m < 4; m++) {
      unsigned u = uu[m];
      atomicAdd(&hist[w][(u & 0xffffu) >> 6], 1u << (((u >> 5) & 1u) * 16));
      atomicAdd(&hist[w][u >> 22],            1u << (((u >> 21) & 1u) * 16));
    }
  }

  // lane owns words [lane*16, lane*16+16) = bins [lane*32, lane*32+32)
  unsigned hw[16];
  #pragma unroll
  for (int p = 0; p < 4; p++)
    *(uint4*)&hw[p*4] = *(const uint4*)&hist[w][lane*16 + p*4];
  unsigned ltot = 0;
  #pragma unroll
  for (int i = 0; i < 16; i++) ltot += (hw[i] & 0xffffu) + (hw[i] >> 16);

  // wave suffix-scan over lane totals (bins ascend with lane; top = lane 63)
  unsigned v = ltot;
  #pragma unroll
  for (int off = 1; off < 64; off <<= 1) {
    unsigned o = __shfl_down(v, off);
    if (lane + off < 64) v += o;
  }
  unsigned above = v - ltot;
  int pk = -1;
  if (v >= 64u && above < 64u) {
    unsigned c = above; int hbl = 0; unsigned cgl = 0;
    #pragma unroll
    for (int j = 31; j >= 0; j--) {
      unsigned cj = (j & 1) ? (hw[j >> 1] >> 16) : (hw[j >> 1] & 0xffffu);
      unsigned cn = c + cj;
      if (cn >= 64u && c < 64u) { hbl = lane*32 + j; cgl = c; }
      c = cn;
    }
    pk = (hbl << 6) | (int)cgl;
  }
  #pragma unroll
  for (int off = 1; off < 64; off <<= 1) pk = max(pk, __shfl_xor(pk, off));
  const unsigned hb = (unsigned)(pk >> 6);
  const unsigned need2 = 64u - (unsigned)(pk & 63);        // >= 1 guaranteed

  // pass 2: 32 bins over low-5 bits within bin hb (16 packed words)
  if (lane < 16) hist[w][lane] = 0;
  #pragma unroll
  for (int c = 0; c < 8; c++) {
    unsigned uu[4] = {kq[c].x, kq[c].y, kq[c].z, kq[c].w};
    #pragma unroll
    for (int m = 0; m < 4; m++) {
      unsigned klo = uu[m] & 0xffffu, khi = uu[m] >> 16;
      if ((klo >> 5) == hb) atomicAdd(&hist[w][(klo & 31u) >> 1], 1u << ((klo & 1u) * 16));
      if ((khi >> 5) == hb) atomicAdd(&hist[w][(khi & 31u) >> 1], 1u << ((khi & 1u) * 16));
    }
  }
  unsigned wv2 = hist[w][lane >> 1];
  unsigned c2 = (lane & 1) ? (wv2 >> 16) : (wv2 & 0xffffu);
  unsigned s2 = c2;
  #pragma unroll
  for (int off = 1; off < 32; off <<= 1) {
    unsigned o = __shfl_down(s2, off);
    if (lane + off < 32) s2 += o;
  }
  unsigned ab2 = s2 - c2;
  int pk2 = -1;
  if (lane < 32 && s2 >= need2 && ab2 < need2) pk2 = (lane << 6) | (int)ab2;
  #pragma unroll
  for (int off = 1; off < 64; off <<= 1) pk2 = max(pk2, __shfl_xor(pk2, off));
  const unsigned tau = (hb << 5) | (unsigned)(pk2 >> 6);
  const int needeq = (int)need2 - (pk2 & 63);              // >= 1 guaranteed

  // take: exactly 64 selected (ties by ticket); store (byte-off, e-1)
  float zloc = 0.f;
  #pragma unroll
  for (int c = 0; c < 8; c++) {
    int cb0 = c*512 + lane*8;
    unsigned uu[4] = {kq[c].x, kq[c].y, kq[c].z, kq[c].w};
    #pragma unroll
    for (int m = 0; m < 4; m++) {
      #pragma unroll
      for (int h = 0; h < 2; h++) {
        unsigned key = h ? (uu[m] >> 16) : (uu[m] & 0xffffu);
        bool take = key > tau;
        if (!take && key == tau) { int k = atomicAdd(&cnts[w][1], 1); take = (k < needeq); }
        if (take) {
          int slot = atomicAdd(&cnts[w][0], 1);
          unsigned short bits = (key & 0x8000u) ? (unsigned short)(key & 0x7fffu)
                                                : (unsigned short)(~key);
          float e = __expf(bf2f(bits));
          zloc += e;
          pair2[w][slot][0] = (unsigned)(cb0 + m*2 + h) << 9;   // idx * 512 bytes
          pair2[w][slot][1] = __float_as_uint(e - 1.0f);
        }
      }
    }
  }
  #pragma unroll
  for (int off = 32; off > 0; off >>= 1) zloc += __shfl_xor(zloc, off);
  const float invZ = 1.0f / (zloc + (float)(N_ - K_));

  // gather: 64 value rows (bf16), lane covers cols [lane*4, lane*4+4)
  const char* vbb = (const char*)value + ((size_t)b << 21);
  float a0 = 0.f, a1 = 0.f, a2 = 0.f, a3 = 0.f;
  for (int i = 0; i < 64; i++) {
    uint2 pr = *(const uint2*)&pair2[w][i][0];     // broadcast ds_read_b64
    float wt = __uint_as_float(pr.y);
    uint2 vv = *(const uint2*)(vbb + pr.x + lane*8);
    a0 += wt * __uint_as_float(vv.x << 16);
    a1 += wt * __uint_as_float(vv.x & 0xffff0000u);
    a2 += wt * __uint_as_float(vv.y << 16);
    a3 += wt * __uint_as_float(vv.y & 0xffff0000u);
  }
  float4 vs = *(const float4*)(vsum + b*D_ + lane*4);
  float4 o;
  o.x = (a0 + vs.x) * invZ; o.y = (a1 + vs.y) * invZ;
  o.z = (a2 + vs.z) * invZ; o.w = (a3 + vs.w) * invZ;
  *(float4*)(out + (size_t)rowg * D_ + lane*4) = o;
}

extern "C" void kernel_launch(void* const* d_in, const int* in_sizes, int n_in,
                              void* d_out, int out_size, void* d_ws, size_t ws_size,
                              hipStream_t stream) {
  const float* x    = (const float*)d_in[0];
  const float* W    = (const float*)d_in[1];
  const float* bias = (const float*)d_in[2];
  float* out = (float*)d_out;
  char* ws = (char*)d_ws;
  unsigned short* xn    = (unsigned short*)(ws);              //  8 MB  bf16 normed x
  unsigned short* Wb    = (unsigned short*)(ws + 8388608);    // 128 KB bf16 W
  float*          norms = (float*)(ws + 8519680);             //  64 KB
  unsigned short* value = (unsigned short*)(ws + 8585216);    //  8 MB  bf16 value
  float*          vsum  = (float*)(ws + 16973824);            //   4 KB
  unsigned short* S     = (unsigned short*)(ws + 16977920);   // 4 x 32 MB ordered-u16 S

  prep_kernel<<<4161, 256, 0, stream>>>(x, W, xn, norms, Wb, vsum);
  compute_kernel<<<4352, 256, 0, stream>>>(xn, norms, Wb, bias, value, vsum, S);
  select_kernel<<<BN_/4, 256, 0, stream>>>(S, value, vsum, out);
}